// Round 3
// baseline (174.762 us; speedup 1.0000x reference)
//
#include <hip/hip_runtime.h>

// Problem constants
#define HWC (512 * 512)          // H*W = 2^18
#define BATCH 4
#define NPIX (BATCH * HWC)       // total pixels = 1,048,576

// -------------------------------------------------------------------------
// Kernel 1: per-pixel math, cooperative coalesced R/D loads staged through
// LDS. Buffer is reused for D then R with explicit __syncthreads() at each
// transition (R1 lesson: without barriers the compiler hoists the R-writes
// above the D-reads — cross-lane RAW race).
//
// Math per pixel (K=6, C=3):
//   LU(D); X = D^{-1} R[0:3,:]^T; S1c = R X; Sxx=S1c[0:3], Syx=S1c[3:6]
//   Q = Syx inv(Sxx); dx = x - mx; z = [dx, Q dx]
//   z1 = R z; z1[0:3] *= -1; z2 = R^T z1 + m
//   out: x_ = z2[0:3], y_ = z2[3:6], m passthrough
// -------------------------------------------------------------------------
__global__ __launch_bounds__(256, 4) void gpenc_math(
    const float* __restrict__ x,   // (B,3,HW)
    const float* __restrict__ m,   // (B,6,HW)
    const float* __restrict__ R,   // (B,HW,36)
    const float* __restrict__ Dm,  // (B,HW,36)
    float* __restrict__ xout,      // (B,3,HW)
    float* __restrict__ yout,      // (B,3,HW)
    float* __restrict__ mout)      // (B,6,HW)
{
    // 4 waves x 576 float4 = 36 KB; wave w owns lbuf[w*576 .. w*576+575]
    __shared__ float4 lbuf[4 * 576];

    const int t = threadIdx.x;
    const int w = t >> 6;            // wave id in block
    const int l = t & 63;            // lane id
    const int g = blockIdx.x * 256 + t;
    const int b = g >> 18;
    const int p = g & (HWC - 1);

    float4* wbuf = lbuf + w * 576;
    // float4 index of this wave's first pixel's first quad in R/D
    const size_t waveBase4 = ((size_t)blockIdx.x * 256 + (size_t)w * 64) * 9;

    const float4* D4 = reinterpret_cast<const float4*>(Dm);
    const float4* R4 = reinterpret_cast<const float4*>(R);

    // ---- issue ALL global loads up front (latency overlaps staging) ----
    float4 sd[9], sr[9];
#pragma unroll
    for (int i = 0; i < 9; ++i) sd[i] = D4[waveBase4 + (size_t)(i * 64 + l)];
#pragma unroll
    for (int i = 0; i < 9; ++i) sr[i] = R4[waveBase4 + (size_t)(i * 64 + l)];

    const size_t xb = (size_t)b * 3 * HWC + p;
    const size_t mb = (size_t)b * 6 * HWC + p;
    float xv[3], mv[6];
#pragma unroll
    for (int c = 0; c < 3; ++c) xv[c] = x[xb + (size_t)c * HWC];
#pragma unroll
    for (int c = 0; c < 6; ++c) mv[c] = m[mb + (size_t)c * HWC];

    // ---- stage D through LDS ----
#pragma unroll
    for (int i = 0; i < 9; ++i) wbuf[i * 64 + l] = sd[i];
    __syncthreads();
    float d[36];
#pragma unroll
    for (int i = 0; i < 9; ++i) {
        float4 v = wbuf[l * 9 + i];
        d[4*i+0] = v.x; d[4*i+1] = v.y; d[4*i+2] = v.z; d[4*i+3] = v.w;
    }
    __syncthreads();   // all D-reads complete before R overwrites the buffer

    // ---- stage R through LDS ----
#pragma unroll
    for (int i = 0; i < 9; ++i) wbuf[i * 64 + l] = sr[i];

    // ---- LU factorization of D in place (no pivot; D ~ 2I, diag dominant),
    //      overlapped with the R ds_writes landing ----
    float rdiag[6];
#pragma unroll
    for (int k = 0; k < 6; ++k) {
        rdiag[k] = 1.0f / d[k*6 + k];
#pragma unroll
        for (int i = k + 1; i < 6; ++i) {
            float lo = d[i*6 + k] * rdiag[k];
            d[i*6 + k] = lo;
#pragma unroll
            for (int j = k + 1; j < 6; ++j) d[i*6 + j] -= lo * d[k*6 + j];
        }
    }

    __syncthreads();   // R-writes visible before R-reads
    float r[36];
#pragma unroll
    for (int i = 0; i < 9; ++i) {
        float4 v = wbuf[l * 9 + i];
        r[4*i+0] = v.x; r[4*i+1] = v.y; r[4*i+2] = v.z; r[4*i+3] = v.w;
    }

    // ---- Solve D X = W, W[:,c] = R[c,:]^T (c = 0..2) -> X (6x3) ----
    float X[18];
#pragma unroll
    for (int c = 0; c < 3; ++c) {
        float tt[6];
#pragma unroll
        for (int i = 0; i < 6; ++i) {
            float s = r[c*6 + i];
#pragma unroll
            for (int j = 0; j < i; ++j) s -= d[i*6 + j] * tt[j];
            tt[i] = s;
        }
#pragma unroll
        for (int i = 5; i >= 0; --i) {
            float s = tt[i];
#pragma unroll
            for (int j = i + 1; j < 6; ++j) s -= d[i*6 + j] * tt[j];
            tt[i] = s * rdiag[i];
        }
#pragma unroll
        for (int i = 0; i < 6; ++i) X[i*3 + c] = tt[i];
    }

    // ---- S1c = R * X  (6x3) ----
    float s1[18];
#pragma unroll
    for (int i = 0; i < 6; ++i) {
#pragma unroll
        for (int c = 0; c < 3; ++c) {
            float s = 0.0f;
#pragma unroll
            for (int j = 0; j < 6; ++j) s += r[i*6 + j] * X[j*3 + c];
            s1[i*3 + c] = s;
        }
    }

    // ---- inv(Sxx) via adjugate ----
    const float a00 = s1[0], a01 = s1[1], a02 = s1[2];
    const float a10 = s1[3], a11 = s1[4], a12 = s1[5];
    const float a20 = s1[6], a21 = s1[7], a22 = s1[8];
    const float c00 =  (a11*a22 - a12*a21);
    const float c01 = -(a10*a22 - a12*a20);
    const float c02 =  (a10*a21 - a11*a20);
    const float det = a00*c00 + a01*c01 + a02*c02;
    const float rdet = 1.0f / det;
    float iS[9];
    iS[0] = c00 * rdet;
    iS[1] = -(a01*a22 - a02*a21) * rdet;
    iS[2] =  (a01*a12 - a02*a11) * rdet;
    iS[3] = c01 * rdet;
    iS[4] =  (a00*a22 - a02*a20) * rdet;
    iS[5] = -(a00*a12 - a02*a10) * rdet;
    iS[6] = c02 * rdet;
    iS[7] = -(a00*a21 - a01*a20) * rdet;
    iS[8] =  (a00*a11 - a01*a10) * rdet;

    // ---- Q = Syx * inv(Sxx)  (3x3) ----
    float Q[9];
#pragma unroll
    for (int mm = 0; mm < 3; ++mm) {
#pragma unroll
        for (int n = 0; n < 3; ++n) {
            float s = 0.0f;
#pragma unroll
            for (int k = 0; k < 3; ++k) s += s1[(3 + mm)*3 + k] * iS[k*3 + n];
            Q[mm*3 + n] = s;
        }
    }

    // ---- z = [dx, Q dx] ----
    float z[6];
#pragma unroll
    for (int n = 0; n < 3; ++n) z[n] = xv[n] - mv[n];
#pragma unroll
    for (int mm = 0; mm < 3; ++mm) {
        float s = 0.0f;
#pragma unroll
        for (int n = 0; n < 3; ++n) s += Q[mm*3 + n] * z[n];
        z[3 + mm] = s;
    }

    // ---- z1 = R z ; z1[0:3] *= -1 ; z2 = R^T z1 ; out = z2 + m ----
    float z1[6];
#pragma unroll
    for (int n = 0; n < 6; ++n) {
        float s = 0.0f;
#pragma unroll
        for (int mm = 0; mm < 6; ++mm) s += r[n*6 + mm] * z[mm];
        z1[n] = (n < 3) ? -s : s;
    }
    float z2[6];
#pragma unroll
    for (int n = 0; n < 6; ++n) {
        float s = 0.0f;
#pragma unroll
        for (int mm = 0; mm < 6; ++mm) s += z1[mm] * r[mm*6 + n];
        z2[n] = s + mv[n];
    }

    // ---- writes (coalesced plane-strided) ----
#pragma unroll
    for (int c = 0; c < 3; ++c) xout[xb + (size_t)c * HWC] = z2[c];
#pragma unroll
    for (int c = 0; c < 3; ++c) yout[xb + (size_t)c * HWC] = z2[3 + c];
#pragma unroll
    for (int c = 0; c < 6; ++c) mout[mb + (size_t)c * HWC] = mv[c];
}

// -------------------------------------------------------------------------
// Kernel 2: S_out = transpose(S, (0,3,4,1,2))  — already ~BW ceiling, keep.
// -------------------------------------------------------------------------
__global__ __launch_bounds__(256) void gpenc_transpose(
    const float* __restrict__ S,   // (B,HW,36)
    float* __restrict__ Sout)      // (B,36,HW)
{
    const int g = blockIdx.x * 256 + threadIdx.x;
    const int b = g >> 18;
    const int p = g & (HWC - 1);
    const float4* S4 = reinterpret_cast<const float4*>(S + (size_t)g * 36);
    float* out = Sout + (size_t)b * 36 * HWC + p;
#pragma unroll
    for (int i = 0; i < 9; ++i) {
        float4 v = S4[i];
        out[(size_t)(4*i + 0) * HWC] = v.x;
        out[(size_t)(4*i + 1) * HWC] = v.y;
        out[(size_t)(4*i + 2) * HWC] = v.z;
        out[(size_t)(4*i + 3) * HWC] = v.w;
    }
}

extern "C" void kernel_launch(void* const* d_in, const int* in_sizes, int n_in,
                              void* d_out, int out_size, void* d_ws, size_t ws_size,
                              hipStream_t stream) {
    // setup_inputs order: x, y(unused), m, S, R, D
    const float* x  = (const float*)d_in[0];
    const float* m  = (const float*)d_in[2];
    const float* S  = (const float*)d_in[3];
    const float* R  = (const float*)d_in[4];
    const float* D  = (const float*)d_in[5];

    float* out = (float*)d_out;
    const size_t N3 = (size_t)BATCH * 3 * HWC;   // 3,145,728
    const size_t N6 = (size_t)BATCH * 6 * HWC;   // 6,291,456
    float* xout = out;
    float* yout = out + N3;
    float* mout = out + 2 * N3;
    float* Sout = out + 2 * N3 + N6;

    const int threads = 256;
    const int blocks = NPIX / threads;           // 4096

    gpenc_math<<<blocks, threads, 0, stream>>>(x, m, R, D, xout, yout, mout);
    gpenc_transpose<<<blocks, threads, 0, stream>>>(S, Sout);
}

// Round 4
// 169.028 us; speedup vs baseline: 1.0339x; 1.0339x over previous
//
#include <hip/hip_runtime.h>

// Problem constants
#define HWC (512 * 512)           // H*W = 2^18
#define BATCH 4
#define NPIX (BATCH * HWC)        // 1,048,576 pixels
#define NBLK 512                  // 2 blocks per CU, single dispatch round
#define THREADS 256
#define STRIDE (NBLK * THREADS)   // 131072 pixels per iteration round
#define ITERS (NPIX / STRIDE)     // 8 pixels per thread

// -------------------------------------------------------------------------
// Math per pixel (K=6, C=3):
//   LU(D); X = D^{-1} R[0:3,:]^T; S1c = R X; Sxx=S1c[0:3], Syx=S1c[3:6]
//   Q = Syx inv(Sxx); dx = x - mx; z = [dx, Q dx]
//   z1 = R z; z1[0:3] *= -1; z2 = R^T z1 + m
//   out: x_ = z2[0:3], y_ = z2[3:6], m passthrough
//
// R3 structure: register double-buffer software pipeline. While pixel k is
// being computed, pixel k+1's 18 float4 loads (R,D) + 9 scalar loads (x,m)
// are in flight. Compiler emits counted s_waitcnt vmcnt(18) so the prefetch
// stays outstanding across the math (in-order vmcnt queue, m135).
// -------------------------------------------------------------------------

// COMPUTE consumes buf (72 floats: D then R) in place — LU destroys the D
// half, which is dead afterwards (buffer gets overwritten by next prefetch).
__device__ __forceinline__ void compute_pixel(
    float* __restrict__ buf,      // [0:36) = D, [36:72) = R   (registers)
    const float* __restrict__ xm, // [0:3) = x, [3:9) = m      (registers)
    int gk,
    float* __restrict__ xout, float* __restrict__ yout, float* __restrict__ mout)
{
    float* d = buf;
    float* r = buf + 36;

    // ---- LU factorization of D in place (no pivot; D ~ 2I, diag dominant) ----
    float rdiag[6];
#pragma unroll
    for (int k = 0; k < 6; ++k) {
        rdiag[k] = 1.0f / d[k*6 + k];
#pragma unroll
        for (int i = k + 1; i < 6; ++i) {
            float lo = d[i*6 + k] * rdiag[k];
            d[i*6 + k] = lo;
#pragma unroll
            for (int j = k + 1; j < 6; ++j) d[i*6 + j] -= lo * d[k*6 + j];
        }
    }

    // ---- Solve D X = W, W[:,c] = R[c,:]^T (c = 0..2) -> X (6x3) ----
    float X[18];
#pragma unroll
    for (int c = 0; c < 3; ++c) {
        float tt[6];
#pragma unroll
        for (int i = 0; i < 6; ++i) {
            float s = r[c*6 + i];
#pragma unroll
            for (int j = 0; j < i; ++j) s -= d[i*6 + j] * tt[j];
            tt[i] = s;
        }
#pragma unroll
        for (int i = 5; i >= 0; --i) {
            float s = tt[i];
#pragma unroll
            for (int j = i + 1; j < 6; ++j) s -= d[i*6 + j] * tt[j];
            tt[i] = s * rdiag[i];
        }
#pragma unroll
        for (int i = 0; i < 6; ++i) X[i*3 + c] = tt[i];
    }

    // ---- S1c = R * X  (6x3) ----
    float s1[18];
#pragma unroll
    for (int i = 0; i < 6; ++i) {
#pragma unroll
        for (int c = 0; c < 3; ++c) {
            float s = 0.0f;
#pragma unroll
            for (int j = 0; j < 6; ++j) s += r[i*6 + j] * X[j*3 + c];
            s1[i*3 + c] = s;
        }
    }

    // ---- inv(Sxx) via adjugate ----
    const float a00 = s1[0], a01 = s1[1], a02 = s1[2];
    const float a10 = s1[3], a11 = s1[4], a12 = s1[5];
    const float a20 = s1[6], a21 = s1[7], a22 = s1[8];
    const float c00 =  (a11*a22 - a12*a21);
    const float c01 = -(a10*a22 - a12*a20);
    const float c02 =  (a10*a21 - a11*a20);
    const float det = a00*c00 + a01*c01 + a02*c02;
    const float rdet = 1.0f / det;
    float iS[9];
    iS[0] = c00 * rdet;
    iS[1] = -(a01*a22 - a02*a21) * rdet;
    iS[2] =  (a01*a12 - a02*a11) * rdet;
    iS[3] = c01 * rdet;
    iS[4] =  (a00*a22 - a02*a20) * rdet;
    iS[5] = -(a00*a12 - a02*a10) * rdet;
    iS[6] = c02 * rdet;
    iS[7] = -(a00*a21 - a01*a20) * rdet;
    iS[8] =  (a00*a11 - a01*a10) * rdet;

    // ---- Q = Syx * inv(Sxx)  (3x3) ----
    float Q[9];
#pragma unroll
    for (int mm = 0; mm < 3; ++mm) {
#pragma unroll
        for (int n = 0; n < 3; ++n) {
            float s = 0.0f;
#pragma unroll
            for (int k = 0; k < 3; ++k) s += s1[(3 + mm)*3 + k] * iS[k*3 + n];
            Q[mm*3 + n] = s;
        }
    }

    // ---- z = [dx, Q dx] ----
    float z[6];
#pragma unroll
    for (int n = 0; n < 3; ++n) z[n] = xm[n] - xm[3 + n];
#pragma unroll
    for (int mm = 0; mm < 3; ++mm) {
        float s = 0.0f;
#pragma unroll
        for (int n = 0; n < 3; ++n) s += Q[mm*3 + n] * z[n];
        z[3 + mm] = s;
    }

    // ---- z1 = R z ; z1[0:3] *= -1 ; z2 = R^T z1 ; out = z2 + m ----
    float z1[6];
#pragma unroll
    for (int n = 0; n < 6; ++n) {
        float s = 0.0f;
#pragma unroll
        for (int mm = 0; mm < 6; ++mm) s += r[n*6 + mm] * z[mm];
        z1[n] = (n < 3) ? -s : s;
    }
    float z2[6];
#pragma unroll
    for (int n = 0; n < 6; ++n) {
        float s = 0.0f;
#pragma unroll
        for (int mm = 0; mm < 6; ++mm) s += z1[mm] * r[mm*6 + n];
        z2[n] = s + xm[3 + n];
    }

    // ---- writes (coalesced plane-strided) ----
    const int b = gk >> 18;
    const int p = gk & (HWC - 1);
    const size_t xb = (size_t)b * 3 * HWC + p;
    const size_t mb = (size_t)b * 6 * HWC + p;
#pragma unroll
    for (int c = 0; c < 3; ++c) xout[xb + (size_t)c * HWC] = z2[c];
#pragma unroll
    for (int c = 0; c < 3; ++c) yout[xb + (size_t)c * HWC] = z2[3 + c];
#pragma unroll
    for (int c = 0; c < 6; ++c) mout[mb + (size_t)c * HWC] = xm[3 + c];
}

__device__ __forceinline__ void issue_pixel(
    const float4* __restrict__ D4, const float4* __restrict__ R4,
    const float* __restrict__ x, const float* __restrict__ m,
    int gk, float* __restrict__ buf, float* __restrict__ xm)
{
    float4* b4 = reinterpret_cast<float4*>(buf);
    const float4* Dq = D4 + (size_t)gk * 9;
    const float4* Rq = R4 + (size_t)gk * 9;
#pragma unroll
    for (int i = 0; i < 9; ++i) b4[i] = Dq[i];
#pragma unroll
    for (int i = 0; i < 9; ++i) b4[9 + i] = Rq[i];
    const int b = gk >> 18;
    const int p = gk & (HWC - 1);
    const size_t xb = (size_t)b * 3 * HWC + p;
    const size_t mb = (size_t)b * 6 * HWC + p;
#pragma unroll
    for (int c = 0; c < 3; ++c) xm[c] = x[xb + (size_t)c * HWC];
#pragma unroll
    for (int c = 0; c < 6; ++c) xm[3 + c] = m[mb + (size_t)c * HWC];
}

__global__ __launch_bounds__(THREADS, 2) void gpenc_math(
    const float* __restrict__ x,   // (B,3,HW)
    const float* __restrict__ m,   // (B,6,HW)
    const float* __restrict__ R,   // (B,HW,36)
    const float* __restrict__ Dm,  // (B,HW,36)
    float* __restrict__ xout,      // (B,3,HW)
    float* __restrict__ yout,      // (B,3,HW)
    float* __restrict__ mout)      // (B,6,HW)
{
    const int t0 = blockIdx.x * THREADS + threadIdx.x;   // [0, STRIDE)
    const float4* D4 = reinterpret_cast<const float4*>(Dm);
    const float4* R4 = reinterpret_cast<const float4*>(R);

    // register double-buffers (alignas so float4 aliasing is clean)
    __attribute__((aligned(16))) float bufA[72], bufB[72];
    float xmA[9], xmB[9];

    issue_pixel(D4, R4, x, m, t0, bufA, xmA);

#pragma unroll
    for (int k = 0; k < ITERS; ++k) {
        const int gk = t0 + k * STRIDE;
        if ((k & 1) == 0) {
            if (k < ITERS - 1) issue_pixel(D4, R4, x, m, gk + STRIDE, bufB, xmB);
            compute_pixel(bufA, xmA, gk, xout, yout, mout);
        } else {
            if (k < ITERS - 1) issue_pixel(D4, R4, x, m, gk + STRIDE, bufA, xmA);
            compute_pixel(bufB, xmB, gk, xout, yout, mout);
        }
    }
}

// -------------------------------------------------------------------------
// Kernel 2: S_out = transpose(S, (0,3,4,1,2))  — ~7.5 TB/s (L3-fed), keep.
// -------------------------------------------------------------------------
__global__ __launch_bounds__(256) void gpenc_transpose(
    const float* __restrict__ S,   // (B,HW,36)
    float* __restrict__ Sout)      // (B,36,HW)
{
    const int g = blockIdx.x * 256 + threadIdx.x;
    const int b = g >> 18;
    const int p = g & (HWC - 1);
    const float4* S4 = reinterpret_cast<const float4*>(S + (size_t)g * 36);
    float* out = Sout + (size_t)b * 36 * HWC + p;
#pragma unroll
    for (int i = 0; i < 9; ++i) {
        float4 v = S4[i];
        out[(size_t)(4*i + 0) * HWC] = v.x;
        out[(size_t)(4*i + 1) * HWC] = v.y;
        out[(size_t)(4*i + 2) * HWC] = v.z;
        out[(size_t)(4*i + 3) * HWC] = v.w;
    }
}

extern "C" void kernel_launch(void* const* d_in, const int* in_sizes, int n_in,
                              void* d_out, int out_size, void* d_ws, size_t ws_size,
                              hipStream_t stream) {
    // setup_inputs order: x, y(unused), m, S, R, D
    const float* x  = (const float*)d_in[0];
    const float* m  = (const float*)d_in[2];
    const float* S  = (const float*)d_in[3];
    const float* R  = (const float*)d_in[4];
    const float* D  = (const float*)d_in[5];

    float* out = (float*)d_out;
    const size_t N3 = (size_t)BATCH * 3 * HWC;   // 3,145,728
    const size_t N6 = (size_t)BATCH * 6 * HWC;   // 6,291,456
    float* xout = out;
    float* yout = out + N3;
    float* mout = out + 2 * N3;
    float* Sout = out + 2 * N3 + N6;

    gpenc_math<<<NBLK, THREADS, 0, stream>>>(x, m, R, D, xout, yout, mout);
    gpenc_transpose<<<NPIX / 256, 256, 0, stream>>>(S, Sout);
}

// Round 5
// 165.381 us; speedup vs baseline: 1.0567x; 1.0220x over previous
//
#include <hip/hip_runtime.h>

// Problem constants
#define HWC (512 * 512)           // H*W = 2^18
#define BATCH 4
#define NPIX (BATCH * HWC)        // 1,048,576 pixels

// -------------------------------------------------------------------------
// Kernel 1: per-pixel math, FULLY SCALARIZED (no local arrays at all).
// R0/R2/R3 post-mortem: local float arrays (d[36], r[36], buf[72]) were
// never SROA'd to registers (VGPR_Count 40/52/108 << live state) — all
// three kernels were scratch-bound at ~130us regardless of load pattern,
// occupancy, or software pipelining. Named scalars force SSA/registers.
//
// Math per pixel (K=6, C=3):
//   LU(D) (no pivot; D ~ 2I+0.1N, diag dominant)
//   X = D^{-1} R[0:3,:]^T  (3 RHS)
//   S1c = R X; Sxx = S1c[0:3,:], Syx = S1c[3:6,:]
//   Q = Syx inv(Sxx)
//   dx = x - mx; z = [dx, Q dx]
//   z1 = R z; z1[0:3] *= -1; z2 = R^T z1 + m
//   out: x_ = z2[0:3], y_ = z2[3:6], m passthrough
// -------------------------------------------------------------------------

// LU solve, one RHS: in w0..w5, out o0..o5 (uses lij, dij(U), rdk from scope)
#define SOLVE6(w0,w1,w2,w3,w4,w5, o0,o1,o2,o3,o4,o5)                      \
  {                                                                       \
    float t0 = (w0);                                                      \
    float t1 = (w1) - l10*t0;                                             \
    float t2 = (w2) - l20*t0 - l21*t1;                                    \
    float t3 = (w3) - l30*t0 - l31*t1 - l32*t2;                           \
    float t4 = (w4) - l40*t0 - l41*t1 - l42*t2 - l43*t3;                  \
    float t5 = (w5) - l50*t0 - l51*t1 - l52*t2 - l53*t3 - l54*t4;         \
    o5 = t5*rd5;                                                          \
    o4 = (t4 - d45*o5)*rd4;                                               \
    o3 = (t3 - d34*o4 - d35*o5)*rd3;                                      \
    o2 = (t2 - d23*o3 - d24*o4 - d25*o5)*rd2;                             \
    o1 = (t1 - d12*o2 - d13*o3 - d14*o4 - d15*o5)*rd1;                    \
    o0 = (t0 - d01*o1 - d02*o2 - d03*o3 - d04*o4 - d05*o5)*rd0;           \
  }

// s1[i][c] = sum_j r[i][j] * X[j][c]
#define S1(i,c) (r##i##0*X0_##c + r##i##1*X1_##c + r##i##2*X2_##c +       \
                 r##i##3*X3_##c + r##i##4*X4_##c + r##i##5*X5_##c)

__global__ __launch_bounds__(256) void gpenc_math(
    const float* __restrict__ x,   // (B,3,HW)
    const float* __restrict__ m,   // (B,6,HW)
    const float* __restrict__ R,   // (B,HW,36)
    const float* __restrict__ Dm,  // (B,HW,36)
    float* __restrict__ xout,      // (B,3,HW)
    float* __restrict__ yout,      // (B,3,HW)
    float* __restrict__ mout)      // (B,6,HW)
{
    const int g = blockIdx.x * 256 + threadIdx.x;
    const int b = g >> 18;
    const int p = g & (HWC - 1);

    const float4* D4 = reinterpret_cast<const float4*>(Dm + (size_t)g * 36);
    const float4* R4 = reinterpret_cast<const float4*>(R  + (size_t)g * 36);

    // ---- D: 9 float4 -> 36 named scalars (row-major d[i][j]) ----
    float4 qa = D4[0], qb = D4[1], qc = D4[2], qd = D4[3], qe = D4[4],
           qf = D4[5], qg = D4[6], qh = D4[7], qi = D4[8];
    float d00=qa.x, d01=qa.y, d02=qa.z, d03=qa.w;
    float d04=qb.x, d05=qb.y, d10=qb.z, d11=qb.w;
    float d12=qc.x, d13=qc.y, d14=qc.z, d15=qc.w;
    float d20=qd.x, d21=qd.y, d22=qd.z, d23=qd.w;
    float d24=qe.x, d25=qe.y, d30=qe.z, d31=qe.w;
    float d32=qf.x, d33=qf.y, d34=qf.z, d35=qf.w;
    float d40=qg.x, d41=qg.y, d42=qg.z, d43=qg.w;
    float d44=qh.x, d45=qh.y, d50=qh.z, d51=qh.w;
    float d52=qi.x, d53=qi.y, d54=qi.z, d55=qi.w;

    // ---- R: 9 float4 -> 36 named scalars ----
    float4 pa = R4[0], pb = R4[1], pc = R4[2], pd = R4[3], pe = R4[4],
           pf = R4[5], pg = R4[6], ph = R4[7], pi = R4[8];
    float r00=pa.x, r01=pa.y, r02=pa.z, r03=pa.w;
    float r04=pb.x, r05=pb.y, r10=pb.z, r11=pb.w;
    float r12=pc.x, r13=pc.y, r14=pc.z, r15=pc.w;
    float r20=pd.x, r21=pd.y, r22=pd.z, r23=pd.w;
    float r24=pe.x, r25=pe.y, r30=pe.z, r31=pe.w;
    float r32=pf.x, r33=pf.y, r34=pf.z, r35=pf.w;
    float r40=pg.x, r41=pg.y, r42=pg.z, r43=pg.w;
    float r44=ph.x, r45=ph.y, r50=ph.z, r51=ph.w;
    float r52=pi.x, r53=pi.y, r54=pi.z, r55=pi.w;

    // ---- x, m (plane-strided, coalesced across lanes) ----
    const size_t xb = (size_t)b * 3 * HWC + p;
    const size_t mb = (size_t)b * 6 * HWC + p;
    float xv0 = x[xb], xv1 = x[xb + HWC], xv2 = x[xb + 2*HWC];
    float mv0 = m[mb],        mv1 = m[mb + HWC],   mv2 = m[mb + 2*(size_t)HWC];
    float mv3 = m[mb + 3*(size_t)HWC], mv4 = m[mb + 4*(size_t)HWC], mv5 = m[mb + 5*(size_t)HWC];

    // ---- LU of D in place, fully unrolled (Doolittle, no pivot) ----
    float rd0 = 1.0f/d00;
    float l10 = d10*rd0;
    d11 -= l10*d01; d12 -= l10*d02; d13 -= l10*d03; d14 -= l10*d04; d15 -= l10*d05;
    float l20 = d20*rd0;
    d21 -= l20*d01; d22 -= l20*d02; d23 -= l20*d03; d24 -= l20*d04; d25 -= l20*d05;
    float l30 = d30*rd0;
    d31 -= l30*d01; d32 -= l30*d02; d33 -= l30*d03; d34 -= l30*d04; d35 -= l30*d05;
    float l40 = d40*rd0;
    d41 -= l40*d01; d42 -= l40*d02; d43 -= l40*d03; d44 -= l40*d04; d45 -= l40*d05;
    float l50 = d50*rd0;
    d51 -= l50*d01; d52 -= l50*d02; d53 -= l50*d03; d54 -= l50*d04; d55 -= l50*d05;

    float rd1 = 1.0f/d11;
    float l21 = d21*rd1;
    d22 -= l21*d12; d23 -= l21*d13; d24 -= l21*d14; d25 -= l21*d15;
    float l31 = d31*rd1;
    d32 -= l31*d12; d33 -= l31*d13; d34 -= l31*d14; d35 -= l31*d15;
    float l41 = d41*rd1;
    d42 -= l41*d12; d43 -= l41*d13; d44 -= l41*d14; d45 -= l41*d15;
    float l51 = d51*rd1;
    d52 -= l51*d12; d53 -= l51*d13; d54 -= l51*d14; d55 -= l51*d15;

    float rd2 = 1.0f/d22;
    float l32 = d32*rd2;
    d33 -= l32*d23; d34 -= l32*d24; d35 -= l32*d25;
    float l42 = d42*rd2;
    d43 -= l42*d23; d44 -= l42*d24; d45 -= l42*d25;
    float l52 = d52*rd2;
    d53 -= l52*d23; d54 -= l52*d24; d55 -= l52*d25;

    float rd3 = 1.0f/d33;
    float l43 = d43*rd3;
    d44 -= l43*d34; d45 -= l43*d35;
    float l53 = d53*rd3;
    d54 -= l53*d34; d55 -= l53*d35;

    float rd4 = 1.0f/d44;
    float l54 = d54*rd4;
    d55 -= l54*d45;
    float rd5 = 1.0f/d55;

    // ---- X = D^{-1} * R[0:3,:]^T  (X[j][c], c = RHS index = R row) ----
    float X0_0,X1_0,X2_0,X3_0,X4_0,X5_0;
    float X0_1,X1_1,X2_1,X3_1,X4_1,X5_1;
    float X0_2,X1_2,X2_2,X3_2,X4_2,X5_2;
    SOLVE6(r00,r01,r02,r03,r04,r05, X0_0,X1_0,X2_0,X3_0,X4_0,X5_0);
    SOLVE6(r10,r11,r12,r13,r14,r15, X0_1,X1_1,X2_1,X3_1,X4_1,X5_1);
    SOLVE6(r20,r21,r22,r23,r24,r25, X0_2,X1_2,X2_2,X3_2,X4_2,X5_2);

    // ---- S1c = R * X : Sxx = rows 0..2 (a**), Syx = rows 3..5 (b**) ----
    float a00=S1(0,0), a01=S1(0,1), a02=S1(0,2);
    float a10=S1(1,0), a11=S1(1,1), a12=S1(1,2);
    float a20=S1(2,0), a21=S1(2,1), a22=S1(2,2);
    float b00=S1(3,0), b01=S1(3,1), b02=S1(3,2);
    float b10=S1(4,0), b11=S1(4,1), b12=S1(4,2);
    float b20=S1(5,0), b21=S1(5,1), b22=S1(5,2);

    // ---- inv(Sxx) via adjugate ----
    float c00 =  (a11*a22 - a12*a21);
    float c01 = -(a10*a22 - a12*a20);
    float c02 =  (a10*a21 - a11*a20);
    float det = a00*c00 + a01*c01 + a02*c02;
    float rdet = 1.0f / det;
    float i00 = c00*rdet;
    float i01 = -(a01*a22 - a02*a21)*rdet;
    float i02 =  (a01*a12 - a02*a11)*rdet;
    float i10 = c01*rdet;
    float i11 =  (a00*a22 - a02*a20)*rdet;
    float i12 = -(a00*a12 - a02*a10)*rdet;
    float i20 = c02*rdet;
    float i21 = -(a00*a21 - a01*a20)*rdet;
    float i22 =  (a00*a11 - a01*a10)*rdet;

    // ---- Q = Syx * inv(Sxx) ----
    float Q00 = b00*i00 + b01*i10 + b02*i20;
    float Q01 = b00*i01 + b01*i11 + b02*i21;
    float Q02 = b00*i02 + b01*i12 + b02*i22;
    float Q10 = b10*i00 + b11*i10 + b12*i20;
    float Q11 = b10*i01 + b11*i11 + b12*i21;
    float Q12 = b10*i02 + b11*i12 + b12*i22;
    float Q20 = b20*i00 + b21*i10 + b22*i20;
    float Q21 = b20*i01 + b21*i11 + b22*i21;
    float Q22 = b20*i02 + b21*i12 + b22*i22;

    // ---- z = [dx, Q dx] ----
    float z0 = xv0 - mv0, z1v = xv1 - mv1, z2v = xv2 - mv2;
    float z3 = Q00*z0 + Q01*z1v + Q02*z2v;
    float z4 = Q10*z0 + Q11*z1v + Q12*z2v;
    float z5 = Q20*z0 + Q21*z1v + Q22*z2v;

    // ---- w = R z, rows 0..2 negated ----
    float w0 = -(r00*z0 + r01*z1v + r02*z2v + r03*z3 + r04*z4 + r05*z5);
    float w1 = -(r10*z0 + r11*z1v + r12*z2v + r13*z3 + r14*z4 + r15*z5);
    float w2 = -(r20*z0 + r21*z1v + r22*z2v + r23*z3 + r24*z4 + r25*z5);
    float w3 =  (r30*z0 + r31*z1v + r32*z2v + r33*z3 + r34*z4 + r35*z5);
    float w4 =  (r40*z0 + r41*z1v + r42*z2v + r43*z3 + r44*z4 + r45*z5);
    float w5 =  (r50*z0 + r51*z1v + r52*z2v + r53*z3 + r54*z4 + r55*z5);

    // ---- z2 = R^T w + m ----
    float o0 = w0*r00 + w1*r10 + w2*r20 + w3*r30 + w4*r40 + w5*r50 + mv0;
    float o1 = w0*r01 + w1*r11 + w2*r21 + w3*r31 + w4*r41 + w5*r51 + mv1;
    float o2 = w0*r02 + w1*r12 + w2*r22 + w3*r32 + w4*r42 + w5*r52 + mv2;
    float o3 = w0*r03 + w1*r13 + w2*r23 + w3*r33 + w4*r43 + w5*r53 + mv3;
    float o4 = w0*r04 + w1*r14 + w2*r24 + w3*r34 + w4*r44 + w5*r54 + mv4;
    float o5 = w0*r05 + w1*r15 + w2*r25 + w3*r35 + w4*r45 + w5*r55 + mv5;

    // ---- writes (coalesced plane-strided) ----
    xout[xb] = o0; xout[xb + HWC] = o1; xout[xb + 2*(size_t)HWC] = o2;
    yout[xb] = o3; yout[xb + HWC] = o4; yout[xb + 2*(size_t)HWC] = o5;
    mout[mb]                    = mv0;
    mout[mb + (size_t)HWC]      = mv1;
    mout[mb + 2*(size_t)HWC]    = mv2;
    mout[mb + 3*(size_t)HWC]    = mv3;
    mout[mb + 4*(size_t)HWC]    = mv4;
    mout[mb + 5*(size_t)HWC]    = mv5;
}

// -------------------------------------------------------------------------
// Kernel 2: S_out = transpose(S, (0,3,4,1,2))  — ~BW ceiling already, keep.
// -------------------------------------------------------------------------
__global__ __launch_bounds__(256) void gpenc_transpose(
    const float* __restrict__ S,   // (B,HW,36)
    float* __restrict__ Sout)      // (B,36,HW)
{
    const int g = blockIdx.x * 256 + threadIdx.x;
    const int b = g >> 18;
    const int p = g & (HWC - 1);
    const float4* S4 = reinterpret_cast<const float4*>(S + (size_t)g * 36);
    float* out = Sout + (size_t)b * 36 * HWC + p;
#pragma unroll
    for (int i = 0; i < 9; ++i) {
        float4 v = S4[i];
        out[(size_t)(4*i + 0) * HWC] = v.x;
        out[(size_t)(4*i + 1) * HWC] = v.y;
        out[(size_t)(4*i + 2) * HWC] = v.z;
        out[(size_t)(4*i + 3) * HWC] = v.w;
    }
}

extern "C" void kernel_launch(void* const* d_in, const int* in_sizes, int n_in,
                              void* d_out, int out_size, void* d_ws, size_t ws_size,
                              hipStream_t stream) {
    // setup_inputs order: x, y(unused), m, S, R, D
    const float* x  = (const float*)d_in[0];
    const float* m  = (const float*)d_in[2];
    const float* S  = (const float*)d_in[3];
    const float* R  = (const float*)d_in[4];
    const float* D  = (const float*)d_in[5];

    float* out = (float*)d_out;
    const size_t N3 = (size_t)BATCH * 3 * HWC;   // 3,145,728
    const size_t N6 = (size_t)BATCH * 6 * HWC;   // 6,291,456
    float* xout = out;
    float* yout = out + N3;
    float* mout = out + 2 * N3;
    float* Sout = out + 2 * N3 + N6;

    gpenc_math<<<NPIX / 256, 256, 0, stream>>>(x, m, R, D, xout, yout, mout);
    gpenc_transpose<<<NPIX / 256, 256, 0, stream>>>(S, Sout);
}

// Round 6
// 159.077 us; speedup vs baseline: 1.0986x; 1.0396x over previous
//
#include <hip/hip_runtime.h>

// Problem constants
#define HWC (512 * 512)           // H*W = 2^18
#define BATCH 4
#define NPIX (BATCH * HWC)        // 1,048,576 pixels

// -------------------------------------------------------------------------
// R5: scalar math kernel + REGISTER-PINNED loads.
// R0..R4 post-mortem: compiler allocated only 40 VGPRs (live set ~100) by
// sinking/re-issuing the __restrict__ global loads before each use ->
// serial load->wait->compute chains, ~130us regardless of structure.
// Fix: load everything up front, then pin every loaded value with
// asm volatile("" : "+v"(v)) so it cannot be rematerialized by reloading.
// __launch_bounds__(256,4) raises the VGPR budget to 128/wave.
// -------------------------------------------------------------------------

#define PIN8(a,b,c,d,e,f,g,h) asm volatile("" : "+v"(a),"+v"(b),"+v"(c),"+v"(d),"+v"(e),"+v"(f),"+v"(g),"+v"(h))
#define PIN4(a,b,c,d)         asm volatile("" : "+v"(a),"+v"(b),"+v"(c),"+v"(d))
#define PIN3(a,b,c)           asm volatile("" : "+v"(a),"+v"(b),"+v"(c))
#define PIN6(a,b,c,d,e,f)     asm volatile("" : "+v"(a),"+v"(b),"+v"(c),"+v"(d),"+v"(e),"+v"(f))

// LU solve, one RHS: in w0..w5, out o0..o5 (uses lij, dij(U), rdk from scope)
#define SOLVE6(w0,w1,w2,w3,w4,w5, o0,o1,o2,o3,o4,o5)                      \
  {                                                                       \
    float t0 = (w0);                                                      \
    float t1 = (w1) - l10*t0;                                             \
    float t2 = (w2) - l20*t0 - l21*t1;                                    \
    float t3 = (w3) - l30*t0 - l31*t1 - l32*t2;                           \
    float t4 = (w4) - l40*t0 - l41*t1 - l42*t2 - l43*t3;                  \
    float t5 = (w5) - l50*t0 - l51*t1 - l52*t2 - l53*t3 - l54*t4;         \
    o5 = t5*rd5;                                                          \
    o4 = (t4 - d45*o5)*rd4;                                               \
    o3 = (t3 - d34*o4 - d35*o5)*rd3;                                      \
    o2 = (t2 - d23*o3 - d24*o4 - d25*o5)*rd2;                             \
    o1 = (t1 - d12*o2 - d13*o3 - d14*o4 - d15*o5)*rd1;                    \
    o0 = (t0 - d01*o1 - d02*o2 - d03*o3 - d04*o4 - d05*o5)*rd0;           \
  }

// s1[i][c] = sum_j r[i][j] * X[j][c]
#define S1(i,c) (r##i##0*X0_##c + r##i##1*X1_##c + r##i##2*X2_##c +       \
                 r##i##3*X3_##c + r##i##4*X4_##c + r##i##5*X5_##c)

__global__ __launch_bounds__(256, 4) void gpenc_math(
    const float* __restrict__ x,   // (B,3,HW)
    const float* __restrict__ m,   // (B,6,HW)
    const float* __restrict__ R,   // (B,HW,36)
    const float* __restrict__ Dm,  // (B,HW,36)
    float* __restrict__ xout,      // (B,3,HW)
    float* __restrict__ yout,      // (B,3,HW)
    float* __restrict__ mout)      // (B,6,HW)
{
    const int g = blockIdx.x * 256 + threadIdx.x;
    const int b = g >> 18;
    const int p = g & (HWC - 1);

    const float4* D4 = reinterpret_cast<const float4*>(Dm + (size_t)g * 36);
    const float4* R4 = reinterpret_cast<const float4*>(R  + (size_t)g * 36);

    // ---- issue ALL loads up front ----
    float4 qa = D4[0], qb = D4[1], qc = D4[2], qd = D4[3], qe = D4[4],
           qf = D4[5], qg = D4[6], qh = D4[7], qi = D4[8];
    float4 pa = R4[0], pb = R4[1], pc = R4[2], pd = R4[3], pe = R4[4],
           pf = R4[5], pg = R4[6], ph = R4[7], pi = R4[8];

    const size_t xb = (size_t)b * 3 * HWC + p;
    const size_t mb = (size_t)b * 6 * HWC + p;
    float xv0 = x[xb], xv1 = x[xb + HWC], xv2 = x[xb + 2*(size_t)HWC];
    float mv0 = m[mb],                 mv1 = m[mb + (size_t)HWC],   mv2 = m[mb + 2*(size_t)HWC];
    float mv3 = m[mb + 3*(size_t)HWC], mv4 = m[mb + 4*(size_t)HWC], mv5 = m[mb + 5*(size_t)HWC];

    // ---- unpack to named scalars ----
    float d00=qa.x, d01=qa.y, d02=qa.z, d03=qa.w;
    float d04=qb.x, d05=qb.y, d10=qb.z, d11=qb.w;
    float d12=qc.x, d13=qc.y, d14=qc.z, d15=qc.w;
    float d20=qd.x, d21=qd.y, d22=qd.z, d23=qd.w;
    float d24=qe.x, d25=qe.y, d30=qe.z, d31=qe.w;
    float d32=qf.x, d33=qf.y, d34=qf.z, d35=qf.w;
    float d40=qg.x, d41=qg.y, d42=qg.z, d43=qg.w;
    float d44=qh.x, d45=qh.y, d50=qh.z, d51=qh.w;
    float d52=qi.x, d53=qi.y, d54=qi.z, d55=qi.w;

    float r00=pa.x, r01=pa.y, r02=pa.z, r03=pa.w;
    float r04=pb.x, r05=pb.y, r10=pb.z, r11=pb.w;
    float r12=pc.x, r13=pc.y, r14=pc.z, r15=pc.w;
    float r20=pd.x, r21=pd.y, r22=pd.z, r23=pd.w;
    float r24=pe.x, r25=pe.y, r30=pe.z, r31=pe.w;
    float r32=pf.x, r33=pf.y, r34=pf.z, r35=pf.w;
    float r40=pg.x, r41=pg.y, r42=pg.z, r43=pg.w;
    float r44=ph.x, r45=ph.y, r50=ph.z, r51=ph.w;
    float r52=pi.x, r53=pi.y, r54=pi.z, r55=pi.w;

    // ---- pin every loaded value in a VGPR (kills reload-rematerialization) ----
    PIN8(d00,d01,d02,d03,d04,d05,d10,d11);
    PIN8(d12,d13,d14,d15,d20,d21,d22,d23);
    PIN8(d24,d25,d30,d31,d32,d33,d34,d35);
    PIN8(d40,d41,d42,d43,d44,d45,d50,d51);
    PIN4(d52,d53,d54,d55);
    PIN8(r00,r01,r02,r03,r04,r05,r10,r11);
    PIN8(r12,r13,r14,r15,r20,r21,r22,r23);
    PIN8(r24,r25,r30,r31,r32,r33,r34,r35);
    PIN8(r40,r41,r42,r43,r44,r45,r50,r51);
    PIN4(r52,r53,r54,r55);
    PIN3(xv0,xv1,xv2);
    PIN6(mv0,mv1,mv2,mv3,mv4,mv5);

    // ---- LU of D in place, fully unrolled (Doolittle, no pivot) ----
    float rd0 = 1.0f/d00;
    float l10 = d10*rd0;
    d11 -= l10*d01; d12 -= l10*d02; d13 -= l10*d03; d14 -= l10*d04; d15 -= l10*d05;
    float l20 = d20*rd0;
    d21 -= l20*d01; d22 -= l20*d02; d23 -= l20*d03; d24 -= l20*d04; d25 -= l20*d05;
    float l30 = d30*rd0;
    d31 -= l30*d01; d32 -= l30*d02; d33 -= l30*d03; d34 -= l30*d04; d35 -= l30*d05;
    float l40 = d40*rd0;
    d41 -= l40*d01; d42 -= l40*d02; d43 -= l40*d03; d44 -= l40*d04; d45 -= l40*d05;
    float l50 = d50*rd0;
    d51 -= l50*d01; d52 -= l50*d02; d53 -= l50*d03; d54 -= l50*d04; d55 -= l50*d05;

    float rd1 = 1.0f/d11;
    float l21 = d21*rd1;
    d22 -= l21*d12; d23 -= l21*d13; d24 -= l21*d14; d25 -= l21*d15;
    float l31 = d31*rd1;
    d32 -= l31*d12; d33 -= l31*d13; d34 -= l31*d14; d35 -= l31*d15;
    float l41 = d41*rd1;
    d42 -= l41*d12; d43 -= l41*d13; d44 -= l41*d14; d45 -= l41*d15;
    float l51 = d51*rd1;
    d52 -= l51*d12; d53 -= l51*d13; d54 -= l51*d14; d55 -= l51*d15;

    float rd2 = 1.0f/d22;
    float l32 = d32*rd2;
    d33 -= l32*d23; d34 -= l32*d24; d35 -= l32*d25;
    float l42 = d42*rd2;
    d43 -= l42*d23; d44 -= l42*d24; d45 -= l42*d25;
    float l52 = d52*rd2;
    d53 -= l52*d23; d54 -= l52*d24; d55 -= l52*d25;

    float rd3 = 1.0f/d33;
    float l43 = d43*rd3;
    d44 -= l43*d34; d45 -= l43*d35;
    float l53 = d53*rd3;
    d54 -= l53*d34; d55 -= l53*d35;

    float rd4 = 1.0f/d44;
    float l54 = d54*rd4;
    d55 -= l54*d45;
    float rd5 = 1.0f/d55;

    // ---- X = D^{-1} * R[0:3,:]^T ----
    float X0_0,X1_0,X2_0,X3_0,X4_0,X5_0;
    float X0_1,X1_1,X2_1,X3_1,X4_1,X5_1;
    float X0_2,X1_2,X2_2,X3_2,X4_2,X5_2;
    SOLVE6(r00,r01,r02,r03,r04,r05, X0_0,X1_0,X2_0,X3_0,X4_0,X5_0);
    SOLVE6(r10,r11,r12,r13,r14,r15, X0_1,X1_1,X2_1,X3_1,X4_1,X5_1);
    SOLVE6(r20,r21,r22,r23,r24,r25, X0_2,X1_2,X2_2,X3_2,X4_2,X5_2);

    // ---- S1c = R * X : Sxx rows 0..2 (a**), Syx rows 3..5 (b**) ----
    float a00=S1(0,0), a01=S1(0,1), a02=S1(0,2);
    float a10=S1(1,0), a11=S1(1,1), a12=S1(1,2);
    float a20=S1(2,0), a21=S1(2,1), a22=S1(2,2);
    float b00=S1(3,0), b01=S1(3,1), b02=S1(3,2);
    float b10=S1(4,0), b11=S1(4,1), b12=S1(4,2);
    float b20=S1(5,0), b21=S1(5,1), b22=S1(5,2);

    // ---- inv(Sxx) via adjugate ----
    float c00 =  (a11*a22 - a12*a21);
    float c01 = -(a10*a22 - a12*a20);
    float c02 =  (a10*a21 - a11*a20);
    float det = a00*c00 + a01*c01 + a02*c02;
    float rdet = 1.0f / det;
    float i00 = c00*rdet;
    float i01 = -(a01*a22 - a02*a21)*rdet;
    float i02 =  (a01*a12 - a02*a11)*rdet;
    float i10 = c01*rdet;
    float i11 =  (a00*a22 - a02*a20)*rdet;
    float i12 = -(a00*a12 - a02*a10)*rdet;
    float i20 = c02*rdet;
    float i21 = -(a00*a21 - a01*a20)*rdet;
    float i22 =  (a00*a11 - a01*a10)*rdet;

    // ---- Q = Syx * inv(Sxx) ----
    float Q00 = b00*i00 + b01*i10 + b02*i20;
    float Q01 = b00*i01 + b01*i11 + b02*i21;
    float Q02 = b00*i02 + b01*i12 + b02*i22;
    float Q10 = b10*i00 + b11*i10 + b12*i20;
    float Q11 = b10*i01 + b11*i11 + b12*i21;
    float Q12 = b10*i02 + b11*i12 + b12*i22;
    float Q20 = b20*i00 + b21*i10 + b22*i20;
    float Q21 = b20*i01 + b21*i11 + b22*i21;
    float Q22 = b20*i02 + b21*i12 + b22*i22;

    // ---- z = [dx, Q dx] ----
    float z0 = xv0 - mv0, z1v = xv1 - mv1, z2v = xv2 - mv2;
    float z3 = Q00*z0 + Q01*z1v + Q02*z2v;
    float z4 = Q10*z0 + Q11*z1v + Q12*z2v;
    float z5 = Q20*z0 + Q21*z1v + Q22*z2v;

    // ---- w = R z, rows 0..2 negated ----
    float w0 = -(r00*z0 + r01*z1v + r02*z2v + r03*z3 + r04*z4 + r05*z5);
    float w1 = -(r10*z0 + r11*z1v + r12*z2v + r13*z3 + r14*z4 + r15*z5);
    float w2 = -(r20*z0 + r21*z1v + r22*z2v + r23*z3 + r24*z4 + r25*z5);
    float w3 =  (r30*z0 + r31*z1v + r32*z2v + r33*z3 + r34*z4 + r35*z5);
    float w4 =  (r40*z0 + r41*z1v + r42*z2v + r43*z3 + r44*z4 + r45*z5);
    float w5 =  (r50*z0 + r51*z1v + r52*z2v + r53*z3 + r54*z4 + r55*z5);

    // ---- z2 = R^T w + m ----
    float o0 = w0*r00 + w1*r10 + w2*r20 + w3*r30 + w4*r40 + w5*r50 + mv0;
    float o1 = w0*r01 + w1*r11 + w2*r21 + w3*r31 + w4*r41 + w5*r51 + mv1;
    float o2 = w0*r02 + w1*r12 + w2*r22 + w3*r32 + w4*r42 + w5*r52 + mv2;
    float o3 = w0*r03 + w1*r13 + w2*r23 + w3*r33 + w4*r43 + w5*r53 + mv3;
    float o4 = w0*r04 + w1*r14 + w2*r24 + w3*r34 + w4*r44 + w5*r54 + mv4;
    float o5 = w0*r05 + w1*r15 + w2*r25 + w3*r35 + w4*r45 + w5*r55 + mv5;

    // ---- writes (coalesced plane-strided) ----
    xout[xb] = o0; xout[xb + (size_t)HWC] = o1; xout[xb + 2*(size_t)HWC] = o2;
    yout[xb] = o3; yout[xb + (size_t)HWC] = o4; yout[xb + 2*(size_t)HWC] = o5;
    mout[mb]                    = mv0;
    mout[mb + (size_t)HWC]      = mv1;
    mout[mb + 2*(size_t)HWC]    = mv2;
    mout[mb + 3*(size_t)HWC]    = mv3;
    mout[mb + 4*(size_t)HWC]    = mv4;
    mout[mb + 5*(size_t)HWC]    = mv5;
}

// -------------------------------------------------------------------------
// Kernel 2: S_out = transpose(S, (0,3,4,1,2))  — ~BW ceiling already, keep.
// -------------------------------------------------------------------------
__global__ __launch_bounds__(256) void gpenc_transpose(
    const float* __restrict__ S,   // (B,HW,36)
    float* __restrict__ Sout)      // (B,36,HW)
{
    const int g = blockIdx.x * 256 + threadIdx.x;
    const int b = g >> 18;
    const int p = g & (HWC - 1);
    const float4* S4 = reinterpret_cast<const float4*>(S + (size_t)g * 36);
    float* out = Sout + (size_t)b * 36 * HWC + p;
#pragma unroll
    for (int i = 0; i < 9; ++i) {
        float4 v = S4[i];
        out[(size_t)(4*i + 0) * HWC] = v.x;
        out[(size_t)(4*i + 1) * HWC] = v.y;
        out[(size_t)(4*i + 2) * HWC] = v.z;
        out[(size_t)(4*i + 3) * HWC] = v.w;
    }
}

extern "C" void kernel_launch(void* const* d_in, const int* in_sizes, int n_in,
                              void* d_out, int out_size, void* d_ws, size_t ws_size,
                              hipStream_t stream) {
    // setup_inputs order: x, y(unused), m, S, R, D
    const float* x  = (const float*)d_in[0];
    const float* m  = (const float*)d_in[2];
    const float* S  = (const float*)d_in[3];
    const float* R  = (const float*)d_in[4];
    const float* D  = (const float*)d_in[5];

    float* out = (float*)d_out;
    const size_t N3 = (size_t)BATCH * 3 * HWC;   // 3,145,728
    const size_t N6 = (size_t)BATCH * 6 * HWC;   // 6,291,456
    float* xout = out;
    float* yout = out + N3;
    float* mout = out + 2 * N3;
    float* Sout = out + 2 * N3 + N6;

    gpenc_math<<<NPIX / 256, 256, 0, stream>>>(x, m, R, D, xout, yout, mout);
    gpenc_transpose<<<NPIX / 256, 256, 0, stream>>>(S, Sout);
}

// Round 7
// 148.730 us; speedup vs baseline: 1.1750x; 1.0696x over previous
//
#include <hip/hip_runtime.h>

// Problem constants
#define HWC (512 * 512)           // H*W = 2^18
#define BATCH 4
#define NPIX (BATCH * HWC)        // 1,048,576 pixels

// -------------------------------------------------------------------------
// R6: ONE fused kernel = S-transpose + per-pixel math.
// R0-R5 lesson: the math is a ~122us latency-bound wall (VALU 12%, HBM 23%,
// occupancy-invariant); the transpose is pure streaming at ~7.9TB/s. Fusing
// lets the transpose's 302MB stream fill the math kernel's idle memory
// slots: S loads issue FIRST (oldest in the in-order vmcnt queue), R/D
// loads queue behind them, S^T stores drain while R/D are still in flight,
// and the math runs once R/D land. One latency exposure, double duty-cycle.
// -------------------------------------------------------------------------

#define PIN8(a,b,c,d,e,f,g,h) asm volatile("" : "+v"(a),"+v"(b),"+v"(c),"+v"(d),"+v"(e),"+v"(f),"+v"(g),"+v"(h))
#define PIN4(a,b,c,d)         asm volatile("" : "+v"(a),"+v"(b),"+v"(c),"+v"(d))
#define PIN3(a,b,c)           asm volatile("" : "+v"(a),"+v"(b),"+v"(c))
#define PIN6(a,b,c,d,e,f)     asm volatile("" : "+v"(a),"+v"(b),"+v"(c),"+v"(d),"+v"(e),"+v"(f))

// LU solve, one RHS: in w0..w5, out o0..o5 (uses lij, dij(U), rdk from scope)
#define SOLVE6(w0,w1,w2,w3,w4,w5, o0,o1,o2,o3,o4,o5)                      \
  {                                                                       \
    float t0 = (w0);                                                      \
    float t1 = (w1) - l10*t0;                                             \
    float t2 = (w2) - l20*t0 - l21*t1;                                    \
    float t3 = (w3) - l30*t0 - l31*t1 - l32*t2;                           \
    float t4 = (w4) - l40*t0 - l41*t1 - l42*t2 - l43*t3;                  \
    float t5 = (w5) - l50*t0 - l51*t1 - l52*t2 - l53*t3 - l54*t4;         \
    o5 = t5*rd5;                                                          \
    o4 = (t4 - d45*o5)*rd4;                                               \
    o3 = (t3 - d34*o4 - d35*o5)*rd3;                                      \
    o2 = (t2 - d23*o3 - d24*o4 - d25*o5)*rd2;                             \
    o1 = (t1 - d12*o2 - d13*o3 - d14*o4 - d15*o5)*rd1;                    \
    o0 = (t0 - d01*o1 - d02*o2 - d03*o3 - d04*o4 - d05*o5)*rd0;           \
  }

// s1[i][c] = sum_j r[i][j] * X[j][c]
#define S1(i,c) (r##i##0*X0_##c + r##i##1*X1_##c + r##i##2*X2_##c +       \
                 r##i##3*X3_##c + r##i##4*X4_##c + r##i##5*X5_##c)

__global__ __launch_bounds__(256, 3) void gpenc_fused(
    const float* __restrict__ x,   // (B,3,HW)
    const float* __restrict__ m,   // (B,6,HW)
    const float* __restrict__ S,   // (B,HW,36)
    const float* __restrict__ R,   // (B,HW,36)
    const float* __restrict__ Dm,  // (B,HW,36)
    float* __restrict__ xout,      // (B,3,HW)
    float* __restrict__ yout,      // (B,3,HW)
    float* __restrict__ mout,      // (B,6,HW)
    float* __restrict__ Sout)      // (B,36,HW)
{
    const int g = blockIdx.x * 256 + threadIdx.x;
    const int b = g >> 18;
    const int p = g & (HWC - 1);

    // ---- S loads FIRST: oldest entries in the in-order vmcnt queue ----
    const float4* S4 = reinterpret_cast<const float4*>(S + (size_t)g * 36);
    float4 sa = S4[0], sb = S4[1], sc = S4[2], sd = S4[3], se = S4[4],
           sf = S4[5], sg = S4[6], sh = S4[7], si4 = S4[8];

    // ---- R/D loads queue behind S ----
    const float4* D4 = reinterpret_cast<const float4*>(Dm + (size_t)g * 36);
    const float4* R4 = reinterpret_cast<const float4*>(R  + (size_t)g * 36);
    float4 qa = D4[0], qb = D4[1], qc = D4[2], qd = D4[3], qe = D4[4],
           qf = D4[5], qg = D4[6], qh = D4[7], qi = D4[8];
    float4 pa = R4[0], pb = R4[1], pc = R4[2], pd = R4[3], pe = R4[4],
           pf = R4[5], pg = R4[6], ph = R4[7], pi = R4[8];

    // ---- S^T stores: compiler waits vmcnt(18) (S only); R/D stay in flight;
    //      36 plane-strided, coalesced-across-lanes, fire-and-forget stores ----
    float* so = Sout + (size_t)b * 36 * HWC + p;
    so[0*(size_t)HWC]  = sa.x; so[1*(size_t)HWC]  = sa.y; so[2*(size_t)HWC]  = sa.z; so[3*(size_t)HWC]  = sa.w;
    so[4*(size_t)HWC]  = sb.x; so[5*(size_t)HWC]  = sb.y; so[6*(size_t)HWC]  = sb.z; so[7*(size_t)HWC]  = sb.w;
    so[8*(size_t)HWC]  = sc.x; so[9*(size_t)HWC]  = sc.y; so[10*(size_t)HWC] = sc.z; so[11*(size_t)HWC] = sc.w;
    so[12*(size_t)HWC] = sd.x; so[13*(size_t)HWC] = sd.y; so[14*(size_t)HWC] = sd.z; so[15*(size_t)HWC] = sd.w;
    so[16*(size_t)HWC] = se.x; so[17*(size_t)HWC] = se.y; so[18*(size_t)HWC] = se.z; so[19*(size_t)HWC] = se.w;
    so[20*(size_t)HWC] = sf.x; so[21*(size_t)HWC] = sf.y; so[22*(size_t)HWC] = sf.z; so[23*(size_t)HWC] = sf.w;
    so[24*(size_t)HWC] = sg.x; so[25*(size_t)HWC] = sg.y; so[26*(size_t)HWC] = sg.z; so[27*(size_t)HWC] = sg.w;
    so[28*(size_t)HWC] = sh.x; so[29*(size_t)HWC] = sh.y; so[30*(size_t)HWC] = sh.z; so[31*(size_t)HWC] = sh.w;
    so[32*(size_t)HWC] = si4.x; so[33*(size_t)HWC] = si4.y; so[34*(size_t)HWC] = si4.z; so[35*(size_t)HWC] = si4.w;

    // ---- x/m loads (used last; latency hides under the LU/solves) ----
    const size_t xb = (size_t)b * 3 * HWC + p;
    const size_t mb = (size_t)b * 6 * HWC + p;
    float xv0 = x[xb], xv1 = x[xb + (size_t)HWC], xv2 = x[xb + 2*(size_t)HWC];
    float mv0 = m[mb],                 mv1 = m[mb + (size_t)HWC],   mv2 = m[mb + 2*(size_t)HWC];
    float mv3 = m[mb + 3*(size_t)HWC], mv4 = m[mb + 4*(size_t)HWC], mv5 = m[mb + 5*(size_t)HWC];

    // ---- unpack to named scalars ----
    float d00=qa.x, d01=qa.y, d02=qa.z, d03=qa.w;
    float d04=qb.x, d05=qb.y, d10=qb.z, d11=qb.w;
    float d12=qc.x, d13=qc.y, d14=qc.z, d15=qc.w;
    float d20=qd.x, d21=qd.y, d22=qd.z, d23=qd.w;
    float d24=qe.x, d25=qe.y, d30=qe.z, d31=qe.w;
    float d32=qf.x, d33=qf.y, d34=qf.z, d35=qf.w;
    float d40=qg.x, d41=qg.y, d42=qg.z, d43=qg.w;
    float d44=qh.x, d45=qh.y, d50=qh.z, d51=qh.w;
    float d52=qi.x, d53=qi.y, d54=qi.z, d55=qi.w;

    float r00=pa.x, r01=pa.y, r02=pa.z, r03=pa.w;
    float r04=pb.x, r05=pb.y, r10=pb.z, r11=pb.w;
    float r12=pc.x, r13=pc.y, r14=pc.z, r15=pc.w;
    float r20=pd.x, r21=pd.y, r22=pd.z, r23=pd.w;
    float r24=pe.x, r25=pe.y, r30=pe.z, r31=pe.w;
    float r32=pf.x, r33=pf.y, r34=pf.z, r35=pf.w;
    float r40=pg.x, r41=pg.y, r42=pg.z, r43=pg.w;
    float r44=ph.x, r45=ph.y, r50=ph.z, r51=ph.w;
    float r52=pi.x, r53=pi.y, r54=pi.z, r55=pi.w;

    // ---- pin loaded values (R5: kills reload-remat; backend may use AGPRs) ----
    PIN8(d00,d01,d02,d03,d04,d05,d10,d11);
    PIN8(d12,d13,d14,d15,d20,d21,d22,d23);
    PIN8(d24,d25,d30,d31,d32,d33,d34,d35);
    PIN8(d40,d41,d42,d43,d44,d45,d50,d51);
    PIN4(d52,d53,d54,d55);
    PIN8(r00,r01,r02,r03,r04,r05,r10,r11);
    PIN8(r12,r13,r14,r15,r20,r21,r22,r23);
    PIN8(r24,r25,r30,r31,r32,r33,r34,r35);
    PIN8(r40,r41,r42,r43,r44,r45,r50,r51);
    PIN4(r52,r53,r54,r55);
    PIN3(xv0,xv1,xv2);
    PIN6(mv0,mv1,mv2,mv3,mv4,mv5);

    // ---- LU of D in place, fully unrolled (Doolittle, no pivot; D ~ 2I) ----
    float rd0 = 1.0f/d00;
    float l10 = d10*rd0;
    d11 -= l10*d01; d12 -= l10*d02; d13 -= l10*d03; d14 -= l10*d04; d15 -= l10*d05;
    float l20 = d20*rd0;
    d21 -= l20*d01; d22 -= l20*d02; d23 -= l20*d03; d24 -= l20*d04; d25 -= l20*d05;
    float l30 = d30*rd0;
    d31 -= l30*d01; d32 -= l30*d02; d33 -= l30*d03; d34 -= l30*d04; d35 -= l30*d05;
    float l40 = d40*rd0;
    d41 -= l40*d01; d42 -= l40*d02; d43 -= l40*d03; d44 -= l40*d04; d45 -= l40*d05;
    float l50 = d50*rd0;
    d51 -= l50*d01; d52 -= l50*d02; d53 -= l50*d03; d54 -= l50*d04; d55 -= l50*d05;

    float rd1 = 1.0f/d11;
    float l21 = d21*rd1;
    d22 -= l21*d12; d23 -= l21*d13; d24 -= l21*d14; d25 -= l21*d15;
    float l31 = d31*rd1;
    d32 -= l31*d12; d33 -= l31*d13; d34 -= l31*d14; d35 -= l31*d15;
    float l41 = d41*rd1;
    d42 -= l41*d12; d43 -= l41*d13; d44 -= l41*d14; d45 -= l41*d15;
    float l51 = d51*rd1;
    d52 -= l51*d12; d53 -= l51*d13; d54 -= l51*d14; d55 -= l51*d15;

    float rd2 = 1.0f/d22;
    float l32 = d32*rd2;
    d33 -= l32*d23; d34 -= l32*d24; d35 -= l32*d25;
    float l42 = d42*rd2;
    d43 -= l42*d23; d44 -= l42*d24; d45 -= l42*d25;
    float l52 = d52*rd2;
    d53 -= l52*d23; d54 -= l52*d24; d55 -= l52*d25;

    float rd3 = 1.0f/d33;
    float l43 = d43*rd3;
    d44 -= l43*d34; d45 -= l43*d35;
    float l53 = d53*rd3;
    d54 -= l53*d34; d55 -= l53*d35;

    float rd4 = 1.0f/d44;
    float l54 = d54*rd4;
    d55 -= l54*d45;
    float rd5 = 1.0f/d55;

    // ---- X = D^{-1} * R[0:3,:]^T ----
    float X0_0,X1_0,X2_0,X3_0,X4_0,X5_0;
    float X0_1,X1_1,X2_1,X3_1,X4_1,X5_1;
    float X0_2,X1_2,X2_2,X3_2,X4_2,X5_2;
    SOLVE6(r00,r01,r02,r03,r04,r05, X0_0,X1_0,X2_0,X3_0,X4_0,X5_0);
    SOLVE6(r10,r11,r12,r13,r14,r15, X0_1,X1_1,X2_1,X3_1,X4_1,X5_1);
    SOLVE6(r20,r21,r22,r23,r24,r25, X0_2,X1_2,X2_2,X3_2,X4_2,X5_2);

    // ---- S1c = R * X : Sxx rows 0..2 (a**), Syx rows 3..5 (b**) ----
    float a00=S1(0,0), a01=S1(0,1), a02=S1(0,2);
    float a10=S1(1,0), a11=S1(1,1), a12=S1(1,2);
    float a20=S1(2,0), a21=S1(2,1), a22=S1(2,2);
    float b00=S1(3,0), b01=S1(3,1), b02=S1(3,2);
    float b10=S1(4,0), b11=S1(4,1), b12=S1(4,2);
    float b20=S1(5,0), b21=S1(5,1), b22=S1(5,2);

    // ---- inv(Sxx) via adjugate ----
    float c00 =  (a11*a22 - a12*a21);
    float c01 = -(a10*a22 - a12*a20);
    float c02 =  (a10*a21 - a11*a20);
    float det = a00*c00 + a01*c01 + a02*c02;
    float rdet = 1.0f / det;
    float i00 = c00*rdet;
    float i01 = -(a01*a22 - a02*a21)*rdet;
    float i02 =  (a01*a12 - a02*a11)*rdet;
    float i10 = c01*rdet;
    float i11 =  (a00*a22 - a02*a20)*rdet;
    float i12 = -(a00*a12 - a02*a10)*rdet;
    float i20 = c02*rdet;
    float i21 = -(a00*a21 - a01*a20)*rdet;
    float i22 =  (a00*a11 - a01*a10)*rdet;

    // ---- Q = Syx * inv(Sxx) ----
    float Q00 = b00*i00 + b01*i10 + b02*i20;
    float Q01 = b00*i01 + b01*i11 + b02*i21;
    float Q02 = b00*i02 + b01*i12 + b02*i22;
    float Q10 = b10*i00 + b11*i10 + b12*i20;
    float Q11 = b10*i01 + b11*i11 + b12*i21;
    float Q12 = b10*i02 + b11*i12 + b12*i22;
    float Q20 = b20*i00 + b21*i10 + b22*i20;
    float Q21 = b20*i01 + b21*i11 + b22*i21;
    float Q22 = b20*i02 + b21*i12 + b22*i22;

    // ---- z = [dx, Q dx] ----
    float z0 = xv0 - mv0, z1v = xv1 - mv1, z2v = xv2 - mv2;
    float z3 = Q00*z0 + Q01*z1v + Q02*z2v;
    float z4 = Q10*z0 + Q11*z1v + Q12*z2v;
    float z5 = Q20*z0 + Q21*z1v + Q22*z2v;

    // ---- w = R z, rows 0..2 negated ----
    float w0 = -(r00*z0 + r01*z1v + r02*z2v + r03*z3 + r04*z4 + r05*z5);
    float w1 = -(r10*z0 + r11*z1v + r12*z2v + r13*z3 + r14*z4 + r15*z5);
    float w2 = -(r20*z0 + r21*z1v + r22*z2v + r23*z3 + r24*z4 + r25*z5);
    float w3 =  (r30*z0 + r31*z1v + r32*z2v + r33*z3 + r34*z4 + r35*z5);
    float w4 =  (r40*z0 + r41*z1v + r42*z2v + r43*z3 + r44*z4 + r45*z5);
    float w5 =  (r50*z0 + r51*z1v + r52*z2v + r53*z3 + r54*z4 + r55*z5);

    // ---- z2 = R^T w + m ----
    float o0 = w0*r00 + w1*r10 + w2*r20 + w3*r30 + w4*r40 + w5*r50 + mv0;
    float o1 = w0*r01 + w1*r11 + w2*r21 + w3*r31 + w4*r41 + w5*r51 + mv1;
    float o2 = w0*r02 + w1*r12 + w2*r22 + w3*r32 + w4*r42 + w5*r52 + mv2;
    float o3 = w0*r03 + w1*r13 + w2*r23 + w3*r33 + w4*r43 + w5*r53 + mv3;
    float o4 = w0*r04 + w1*r14 + w2*r24 + w3*r34 + w4*r44 + w5*r54 + mv4;
    float o5 = w0*r05 + w1*r15 + w2*r25 + w3*r35 + w4*r45 + w5*r55 + mv5;

    // ---- writes (coalesced plane-strided) ----
    xout[xb] = o0; xout[xb + (size_t)HWC] = o1; xout[xb + 2*(size_t)HWC] = o2;
    yout[xb] = o3; yout[xb + (size_t)HWC] = o4; yout[xb + 2*(size_t)HWC] = o5;
    mout[mb]                    = mv0;
    mout[mb + (size_t)HWC]      = mv1;
    mout[mb + 2*(size_t)HWC]    = mv2;
    mout[mb + 3*(size_t)HWC]    = mv3;
    mout[mb + 4*(size_t)HWC]    = mv4;
    mout[mb + 5*(size_t)HWC]    = mv5;
}

extern "C" void kernel_launch(void* const* d_in, const int* in_sizes, int n_in,
                              void* d_out, int out_size, void* d_ws, size_t ws_size,
                              hipStream_t stream) {
    // setup_inputs order: x, y(unused), m, S, R, D
    const float* x  = (const float*)d_in[0];
    const float* m  = (const float*)d_in[2];
    const float* S  = (const float*)d_in[3];
    const float* R  = (const float*)d_in[4];
    const float* D  = (const float*)d_in[5];

    float* out = (float*)d_out;
    const size_t N3 = (size_t)BATCH * 3 * HWC;   // 3,145,728
    const size_t N6 = (size_t)BATCH * 6 * HWC;   // 6,291,456
    float* xout = out;
    float* yout = out + N3;
    float* mout = out + 2 * N3;
    float* Sout = out + 2 * N3 + N6;

    gpenc_fused<<<NPIX / 256, 256, 0, stream>>>(x, m, S, R, D,
                                                xout, yout, mout, Sout);
}

// Round 8
// 138.158 us; speedup vs baseline: 1.2649x; 1.0765x over previous
//
#include <hip/hip_runtime.h>

// Problem constants
#define HWC (512 * 512)           // H*W = 2^18
#define BATCH 4
#define NPIX (BATCH * HWC)        // 1,048,576 pixels

// -------------------------------------------------------------------------
// R7: fused kernel with ASM-FORCED wide loads.
// R0-R6 post-mortem: compiler holds VGPR_Count at 48, so the 27 float4
// loads per pixel issue in register-starved batches -> 6-8 serial HBM
// latency exposures per wave -> ~4.7 B/cyc/CU delivered (half the m13
// ceiling) regardless of source structure. Fix: explicit
// global_load_dwordx4 inline-asm with 27 simultaneously-live "=v" float4
// outputs (regalloc must allocate ~110 VGPRs; asm defs cannot be
// rematerialized), one s_waitcnt vmcnt(0), sched_barrier(0) (rule #18).
// -------------------------------------------------------------------------

typedef float f4 __attribute__((ext_vector_type(4)));

#define GLOAD(dst, addr, off) \
    asm volatile("global_load_dwordx4 %0, %1, off offset:" #off \
                 : "=v"(dst) : "v"(addr))

// LU solve, one RHS: in w0..w5, out o0..o5 (uses lij, dij(U), rdk from scope)
#define SOLVE6(w0,w1,w2,w3,w4,w5, o0,o1,o2,o3,o4,o5)                      \
  {                                                                       \
    float t0 = (w0);                                                      \
    float t1 = (w1) - l10*t0;                                             \
    float t2 = (w2) - l20*t0 - l21*t1;                                    \
    float t3 = (w3) - l30*t0 - l31*t1 - l32*t2;                           \
    float t4 = (w4) - l40*t0 - l41*t1 - l42*t2 - l43*t3;                  \
    float t5 = (w5) - l50*t0 - l51*t1 - l52*t2 - l53*t3 - l54*t4;         \
    o5 = t5*rd5;                                                          \
    o4 = (t4 - d45*o5)*rd4;                                               \
    o3 = (t3 - d34*o4 - d35*o5)*rd3;                                      \
    o2 = (t2 - d23*o3 - d24*o4 - d25*o5)*rd2;                             \
    o1 = (t1 - d12*o2 - d13*o3 - d14*o4 - d15*o5)*rd1;                    \
    o0 = (t0 - d01*o1 - d02*o2 - d03*o3 - d04*o4 - d05*o5)*rd0;           \
  }

// s1[i][c] = sum_j r[i][j] * X[j][c]
#define S1(i,c) (r##i##0*X0_##c + r##i##1*X1_##c + r##i##2*X2_##c +       \
                 r##i##3*X3_##c + r##i##4*X4_##c + r##i##5*X5_##c)

__global__ __launch_bounds__(256, 2) void gpenc_fused(
    const float* __restrict__ x,   // (B,3,HW)
    const float* __restrict__ m,   // (B,6,HW)
    const float* __restrict__ S,   // (B,HW,36)
    const float* __restrict__ R,   // (B,HW,36)
    const float* __restrict__ Dm,  // (B,HW,36)
    float* __restrict__ xout,      // (B,3,HW)
    float* __restrict__ yout,      // (B,3,HW)
    float* __restrict__ mout,      // (B,6,HW)
    float* __restrict__ Sout)      // (B,36,HW)
{
    const int g = blockIdx.x * 256 + threadIdx.x;
    const int b = g >> 18;
    const int p = g & (HWC - 1);

    // ---- x/m loads (C code; compiler's own counted waits can only
    //      over-wait in the shared vmcnt queue -> safe) ----
    const size_t xb = (size_t)b * 3 * HWC + p;
    const size_t mb = (size_t)b * 6 * HWC + p;
    float xv0 = x[xb], xv1 = x[xb + (size_t)HWC], xv2 = x[xb + 2*(size_t)HWC];
    float mv0 = m[mb],                 mv1 = m[mb + (size_t)HWC],   mv2 = m[mb + 2*(size_t)HWC];
    float mv3 = m[mb + 3*(size_t)HWC], mv4 = m[mb + 4*(size_t)HWC], mv5 = m[mb + 5*(size_t)HWC];

    // ---- 27 asm loads, all in flight simultaneously ----
    const float* sp = S  + (size_t)g * 36;
    const float* dp = Dm + (size_t)g * 36;
    const float* rp = R  + (size_t)g * 36;

    f4 s0,s1,s2,s3,s4,s5,s6,s7,s8;
    f4 q0,q1,q2,q3,q4,q5,q6,q7,q8;
    f4 p0,p1,p2,p3,p4,p5,p6,p7,p8;

    GLOAD(s0, sp, 0);   GLOAD(s1, sp, 16);  GLOAD(s2, sp, 32);
    GLOAD(s3, sp, 48);  GLOAD(s4, sp, 64);  GLOAD(s5, sp, 80);
    GLOAD(s6, sp, 96);  GLOAD(s7, sp, 112); GLOAD(s8, sp, 128);

    GLOAD(q0, dp, 0);   GLOAD(q1, dp, 16);  GLOAD(q2, dp, 32);
    GLOAD(q3, dp, 48);  GLOAD(q4, dp, 64);  GLOAD(q5, dp, 80);
    GLOAD(q6, dp, 96);  GLOAD(q7, dp, 112); GLOAD(q8, dp, 128);

    GLOAD(p0, rp, 0);   GLOAD(p1, rp, 16);  GLOAD(p2, rp, 32);
    GLOAD(p3, rp, 48);  GLOAD(p4, rp, 64);  GLOAD(p5, rp, 80);
    GLOAD(p6, rp, 96);  GLOAD(p7, rp, 112); GLOAD(p8, rp, 128);

    // one latency exposure for everything
    asm volatile("s_waitcnt vmcnt(0)" ::: "memory");
    __builtin_amdgcn_sched_barrier(0);   // rule #18: no hoisting past the wait

    // ---- S^T stores (plane-strided, coalesced across lanes) ----
    float* so = Sout + (size_t)b * 36 * HWC + p;
    so[0*(size_t)HWC]  = s0.x; so[1*(size_t)HWC]  = s0.y; so[2*(size_t)HWC]  = s0.z; so[3*(size_t)HWC]  = s0.w;
    so[4*(size_t)HWC]  = s1.x; so[5*(size_t)HWC]  = s1.y; so[6*(size_t)HWC]  = s1.z; so[7*(size_t)HWC]  = s1.w;
    so[8*(size_t)HWC]  = s2.x; so[9*(size_t)HWC]  = s2.y; so[10*(size_t)HWC] = s2.z; so[11*(size_t)HWC] = s2.w;
    so[12*(size_t)HWC] = s3.x; so[13*(size_t)HWC] = s3.y; so[14*(size_t)HWC] = s3.z; so[15*(size_t)HWC] = s3.w;
    so[16*(size_t)HWC] = s4.x; so[17*(size_t)HWC] = s4.y; so[18*(size_t)HWC] = s4.z; so[19*(size_t)HWC] = s4.w;
    so[20*(size_t)HWC] = s5.x; so[21*(size_t)HWC] = s5.y; so[22*(size_t)HWC] = s5.z; so[23*(size_t)HWC] = s5.w;
    so[24*(size_t)HWC] = s6.x; so[25*(size_t)HWC] = s6.y; so[26*(size_t)HWC] = s6.z; so[27*(size_t)HWC] = s6.w;
    so[28*(size_t)HWC] = s7.x; so[29*(size_t)HWC] = s7.y; so[30*(size_t)HWC] = s7.z; so[31*(size_t)HWC] = s7.w;
    so[32*(size_t)HWC] = s8.x; so[33*(size_t)HWC] = s8.y; so[34*(size_t)HWC] = s8.z; so[35*(size_t)HWC] = s8.w;

    // ---- unpack to named scalars ----
    float d00=q0.x, d01=q0.y, d02=q0.z, d03=q0.w;
    float d04=q1.x, d05=q1.y, d10=q1.z, d11=q1.w;
    float d12=q2.x, d13=q2.y, d14=q2.z, d15=q2.w;
    float d20=q3.x, d21=q3.y, d22=q3.z, d23=q3.w;
    float d24=q4.x, d25=q4.y, d30=q4.z, d31=q4.w;
    float d32=q5.x, d33=q5.y, d34=q5.z, d35=q5.w;
    float d40=q6.x, d41=q6.y, d42=q6.z, d43=q6.w;
    float d44=q7.x, d45=q7.y, d50=q7.z, d51=q7.w;
    float d52=q8.x, d53=q8.y, d54=q8.z, d55=q8.w;

    float r00=p0.x, r01=p0.y, r02=p0.z, r03=p0.w;
    float r04=p1.x, r05=p1.y, r10=p1.z, r11=p1.w;
    float r12=p2.x, r13=p2.y, r14=p2.z, r15=p2.w;
    float r20=p3.x, r21=p3.y, r22=p3.z, r23=p3.w;
    float r24=p4.x, r25=p4.y, r30=p4.z, r31=p4.w;
    float r32=p5.x, r33=p5.y, r34=p5.z, r35=p5.w;
    float r40=p6.x, r41=p6.y, r42=p6.z, r43=p6.w;
    float r44=p7.x, r45=p7.y, r50=p7.z, r51=p7.w;
    float r52=p8.x, r53=p8.y, r54=p8.z, r55=p8.w;

    // ---- LU of D in place, fully unrolled (Doolittle, no pivot; D ~ 2I) ----
    float rd0 = 1.0f/d00;
    float l10 = d10*rd0;
    d11 -= l10*d01; d12 -= l10*d02; d13 -= l10*d03; d14 -= l10*d04; d15 -= l10*d05;
    float l20 = d20*rd0;
    d21 -= l20*d01; d22 -= l20*d02; d23 -= l20*d03; d24 -= l20*d04; d25 -= l20*d05;
    float l30 = d30*rd0;
    d31 -= l30*d01; d32 -= l30*d02; d33 -= l30*d03; d34 -= l30*d04; d35 -= l30*d05;
    float l40 = d40*rd0;
    d41 -= l40*d01; d42 -= l40*d02; d43 -= l40*d03; d44 -= l40*d04; d45 -= l40*d05;
    float l50 = d50*rd0;
    d51 -= l50*d01; d52 -= l50*d02; d53 -= l50*d03; d54 -= l50*d04; d55 -= l50*d05;

    float rd1 = 1.0f/d11;
    float l21 = d21*rd1;
    d22 -= l21*d12; d23 -= l21*d13; d24 -= l21*d14; d25 -= l21*d15;
    float l31 = d31*rd1;
    d32 -= l31*d12; d33 -= l31*d13; d34 -= l31*d14; d35 -= l31*d15;
    float l41 = d41*rd1;
    d42 -= l41*d12; d43 -= l41*d13; d44 -= l41*d14; d45 -= l41*d15;
    float l51 = d51*rd1;
    d52 -= l51*d12; d53 -= l51*d13; d54 -= l51*d14; d55 -= l51*d15;

    float rd2 = 1.0f/d22;
    float l32 = d32*rd2;
    d33 -= l32*d23; d34 -= l32*d24; d35 -= l32*d25;
    float l42 = d42*rd2;
    d43 -= l42*d23; d44 -= l42*d24; d45 -= l42*d25;
    float l52 = d52*rd2;
    d53 -= l52*d23; d54 -= l52*d24; d55 -= l52*d25;

    float rd3 = 1.0f/d33;
    float l43 = d43*rd3;
    d44 -= l43*d34; d45 -= l43*d35;
    float l53 = d53*rd3;
    d54 -= l53*d34; d55 -= l53*d35;

    float rd4 = 1.0f/d44;
    float l54 = d54*rd4;
    d55 -= l54*d45;
    float rd5 = 1.0f/d55;

    // ---- X = D^{-1} * R[0:3,:]^T ----
    float X0_0,X1_0,X2_0,X3_0,X4_0,X5_0;
    float X0_1,X1_1,X2_1,X3_1,X4_1,X5_1;
    float X0_2,X1_2,X2_2,X3_2,X4_2,X5_2;
    SOLVE6(r00,r01,r02,r03,r04,r05, X0_0,X1_0,X2_0,X3_0,X4_0,X5_0);
    SOLVE6(r10,r11,r12,r13,r14,r15, X0_1,X1_1,X2_1,X3_1,X4_1,X5_1);
    SOLVE6(r20,r21,r22,r23,r24,r25, X0_2,X1_2,X2_2,X3_2,X4_2,X5_2);

    // ---- S1c = R * X : Sxx rows 0..2 (a**), Syx rows 3..5 (b**) ----
    float a00=S1(0,0), a01=S1(0,1), a02=S1(0,2);
    float a10=S1(1,0), a11=S1(1,1), a12=S1(1,2);
    float a20=S1(2,0), a21=S1(2,1), a22=S1(2,2);
    float b00=S1(3,0), b01=S1(3,1), b02=S1(3,2);
    float b10=S1(4,0), b11=S1(4,1), b12=S1(4,2);
    float b20=S1(5,0), b21=S1(5,1), b22=S1(5,2);

    // ---- inv(Sxx) via adjugate ----
    float c00 =  (a11*a22 - a12*a21);
    float c01 = -(a10*a22 - a12*a20);
    float c02 =  (a10*a21 - a11*a20);
    float det = a00*c00 + a01*c01 + a02*c02;
    float rdet = 1.0f / det;
    float i00 = c00*rdet;
    float i01 = -(a01*a22 - a02*a21)*rdet;
    float i02 =  (a01*a12 - a02*a11)*rdet;
    float i10 = c01*rdet;
    float i11 =  (a00*a22 - a02*a20)*rdet;
    float i12 = -(a00*a12 - a02*a10)*rdet;
    float i20 = c02*rdet;
    float i21 = -(a00*a21 - a01*a20)*rdet;
    float i22 =  (a00*a11 - a01*a10)*rdet;

    // ---- Q = Syx * inv(Sxx) ----
    float Q00 = b00*i00 + b01*i10 + b02*i20;
    float Q01 = b00*i01 + b01*i11 + b02*i21;
    float Q02 = b00*i02 + b01*i12 + b02*i22;
    float Q10 = b10*i00 + b11*i10 + b12*i20;
    float Q11 = b10*i01 + b11*i11 + b12*i21;
    float Q12 = b10*i02 + b11*i12 + b12*i22;
    float Q20 = b20*i00 + b21*i10 + b22*i20;
    float Q21 = b20*i01 + b21*i11 + b22*i21;
    float Q22 = b20*i02 + b21*i12 + b22*i22;

    // ---- z = [dx, Q dx] ----
    float z0 = xv0 - mv0, z1v = xv1 - mv1, z2v = xv2 - mv2;
    float z3 = Q00*z0 + Q01*z1v + Q02*z2v;
    float z4 = Q10*z0 + Q11*z1v + Q12*z2v;
    float z5 = Q20*z0 + Q21*z1v + Q22*z2v;

    // ---- w = R z, rows 0..2 negated ----
    float w0 = -(r00*z0 + r01*z1v + r02*z2v + r03*z3 + r04*z4 + r05*z5);
    float w1 = -(r10*z0 + r11*z1v + r12*z2v + r13*z3 + r14*z4 + r15*z5);
    float w2 = -(r20*z0 + r21*z1v + r22*z2v + r23*z3 + r24*z4 + r25*z5);
    float w3 =  (r30*z0 + r31*z1v + r32*z2v + r33*z3 + r34*z4 + r35*z5);
    float w4 =  (r40*z0 + r41*z1v + r42*z2v + r43*z3 + r44*z4 + r45*z5);
    float w5 =  (r50*z0 + r51*z1v + r52*z2v + r53*z3 + r54*z4 + r55*z5);

    // ---- z2 = R^T w + m ----
    float o0 = w0*r00 + w1*r10 + w2*r20 + w3*r30 + w4*r40 + w5*r50 + mv0;
    float o1 = w0*r01 + w1*r11 + w2*r21 + w3*r31 + w4*r41 + w5*r51 + mv1;
    float o2 = w0*r02 + w1*r12 + w2*r22 + w3*r32 + w4*r42 + w5*r52 + mv2;
    float o3 = w0*r03 + w1*r13 + w2*r23 + w3*r33 + w4*r43 + w5*r53 + mv3;
    float o4 = w0*r04 + w1*r14 + w2*r24 + w3*r34 + w4*r44 + w5*r54 + mv4;
    float o5 = w0*r05 + w1*r15 + w2*r25 + w3*r35 + w4*r45 + w5*r55 + mv5;

    // ---- writes (coalesced plane-strided) ----
    xout[xb] = o0; xout[xb + (size_t)HWC] = o1; xout[xb + 2*(size_t)HWC] = o2;
    yout[xb] = o3; yout[xb + (size_t)HWC] = o4; yout[xb + 2*(size_t)HWC] = o5;
    mout[mb]                    = mv0;
    mout[mb + (size_t)HWC]      = mv1;
    mout[mb + 2*(size_t)HWC]    = mv2;
    mout[mb + 3*(size_t)HWC]    = mv3;
    mout[mb + 4*(size_t)HWC]    = mv4;
    mout[mb + 5*(size_t)HWC]    = mv5;
}

extern "C" void kernel_launch(void* const* d_in, const int* in_sizes, int n_in,
                              void* d_out, int out_size, void* d_ws, size_t ws_size,
                              hipStream_t stream) {
    // setup_inputs order: x, y(unused), m, S, R, D
    const float* x  = (const float*)d_in[0];
    const float* m  = (const float*)d_in[2];
    const float* S  = (const float*)d_in[3];
    const float* R  = (const float*)d_in[4];
    const float* D  = (const float*)d_in[5];

    float* out = (float*)d_out;
    const size_t N3 = (size_t)BATCH * 3 * HWC;   // 3,145,728
    const size_t N6 = (size_t)BATCH * 6 * HWC;   // 6,291,456
    float* xout = out;
    float* yout = out + N3;
    float* mout = out + 2 * N3;
    float* Sout = out + 2 * N3 + N6;

    gpenc_fused<<<NPIX / 256, 256, 0, stream>>>(x, m, S, R, D,
                                                xout, yout, mout, Sout);
}

// Round 9
// 136.219 us; speedup vs baseline: 1.2830x; 1.0142x over previous
//
#include <hip/hip_runtime.h>

// Problem constants
#define HWC (512 * 512)           // H*W = 2^18
#define BATCH 4
#define NPIX (BATCH * HWC)        // 1,048,576 pixels

// -------------------------------------------------------------------------
// R8: fused kernel; S^T via LDS tile (float4 stores), D/R via asm-forced
// loads whose latency hides under the LDS transpose phase, counted
// s_waitcnt vmcnt(9) before math (the 9 S^T stores are provably newer than
// the last D/R load -> outstanding<=9 means all D/R retired).
// -------------------------------------------------------------------------

typedef float f4 __attribute__((ext_vector_type(4)));

#define GLOAD(dst, addr, off) \
    asm volatile("global_load_dwordx4 %0, %1, off offset:" #off \
                 : "=v"(dst) : "v"(addr))

// LU solve, one RHS: in w0..w5, out o0..o5 (uses lij, dij(U), rdk from scope)
#define SOLVE6(w0,w1,w2,w3,w4,w5, o0,o1,o2,o3,o4,o5)                      \
  {                                                                       \
    float t0 = (w0);                                                      \
    float t1 = (w1) - l10*t0;                                             \
    float t2 = (w2) - l20*t0 - l21*t1;                                    \
    float t3 = (w3) - l30*t0 - l31*t1 - l32*t2;                           \
    float t4 = (w4) - l40*t0 - l41*t1 - l42*t2 - l43*t3;                  \
    float t5 = (w5) - l50*t0 - l51*t1 - l52*t2 - l53*t3 - l54*t4;         \
    o5 = t5*rd5;                                                          \
    o4 = (t4 - d45*o5)*rd4;                                               \
    o3 = (t3 - d34*o4 - d35*o5)*rd3;                                      \
    o2 = (t2 - d23*o3 - d24*o4 - d25*o5)*rd2;                             \
    o1 = (t1 - d12*o2 - d13*o3 - d14*o4 - d15*o5)*rd1;                    \
    o0 = (t0 - d01*o1 - d02*o2 - d03*o3 - d04*o4 - d05*o5)*rd0;           \
  }

// s1[i][c] = sum_j r[i][j] * X[j][c]
#define S1(i,c) (r##i##0*X0_##c + r##i##1*X1_##c + r##i##2*X2_##c +       \
                 r##i##3*X3_##c + r##i##4*X4_##c + r##i##5*X5_##c)

#define LROW 260   // LDS row stride in floats (36 rows): odd*4 -> clean banks

__global__ __launch_bounds__(256, 3) void gpenc_fused(
    const float* __restrict__ x,   // (B,3,HW)
    const float* __restrict__ m,   // (B,6,HW)
    const float* __restrict__ S,   // (B,HW,36)
    const float* __restrict__ R,   // (B,HW,36)
    const float* __restrict__ Dm,  // (B,HW,36)
    float* __restrict__ xout,      // (B,3,HW)
    float* __restrict__ yout,      // (B,3,HW)
    float* __restrict__ mout,      // (B,6,HW)
    float* __restrict__ Sout)      // (B,36,HW)
{
    __shared__ float lds[36 * LROW];          // 37.4 KB

    const int t = threadIdx.x;
    const int g = blockIdx.x * 256 + t;
    const int b = g >> 18;                     // blockIdx.x >> 10
    const int p = g & (HWC - 1);
    const int pixbase = (blockIdx.x & 1023) * 256;

    // ---- 1. S loads (C-code; compiler tracks & waits these) ----
    const f4* S4 = reinterpret_cast<const f4*>(S + (size_t)g * 36);
    f4 s0 = S4[0], s1 = S4[1], s2 = S4[2], s3 = S4[3], s4 = S4[4],
       s5 = S4[5], s6 = S4[6], s7 = S4[7], s8 = S4[8];

    // ---- 2. x/m loads (early issue; consumed last) ----
    const size_t xb = (size_t)b * 3 * HWC + p;
    const size_t mb = (size_t)b * 6 * HWC + p;
    float xv0 = x[xb], xv1 = x[xb + (size_t)HWC], xv2 = x[xb + 2*(size_t)HWC];
    float mv0 = m[mb],                 mv1 = m[mb + (size_t)HWC],   mv2 = m[mb + 2*(size_t)HWC];
    float mv3 = m[mb + 3*(size_t)HWC], mv4 = m[mb + 4*(size_t)HWC], mv5 = m[mb + 5*(size_t)HWC];

    // ---- 3. S -> LDS, transposed layout lds[plane][pixel] (conflict-free) ----
    lds[ 0*LROW + t] = s0.x; lds[ 1*LROW + t] = s0.y; lds[ 2*LROW + t] = s0.z; lds[ 3*LROW + t] = s0.w;
    lds[ 4*LROW + t] = s1.x; lds[ 5*LROW + t] = s1.y; lds[ 6*LROW + t] = s1.z; lds[ 7*LROW + t] = s1.w;
    lds[ 8*LROW + t] = s2.x; lds[ 9*LROW + t] = s2.y; lds[10*LROW + t] = s2.z; lds[11*LROW + t] = s2.w;
    lds[12*LROW + t] = s3.x; lds[13*LROW + t] = s3.y; lds[14*LROW + t] = s3.z; lds[15*LROW + t] = s3.w;
    lds[16*LROW + t] = s4.x; lds[17*LROW + t] = s4.y; lds[18*LROW + t] = s4.z; lds[19*LROW + t] = s4.w;
    lds[20*LROW + t] = s5.x; lds[21*LROW + t] = s5.y; lds[22*LROW + t] = s5.z; lds[23*LROW + t] = s5.w;
    lds[24*LROW + t] = s6.x; lds[25*LROW + t] = s6.y; lds[26*LROW + t] = s6.z; lds[27*LROW + t] = s6.w;
    lds[28*LROW + t] = s7.x; lds[29*LROW + t] = s7.y; lds[30*LROW + t] = s7.z; lds[31*LROW + t] = s7.w;
    lds[32*LROW + t] = s8.x; lds[33*LROW + t] = s8.y; lds[34*LROW + t] = s8.z; lds[35*LROW + t] = s8.w;

    // ---- 4. D/R asm loads: in flight across barrier + readback + stores ----
    const float* dp = Dm + (size_t)g * 36;
    const float* rp = R  + (size_t)g * 36;
    f4 q0,q1,q2,q3,q4,q5,q6,q7,q8;
    f4 p0,p1,p2,p3,p4,p5,p6,p7,p8;
    GLOAD(q0, dp, 0);   GLOAD(q1, dp, 16);  GLOAD(q2, dp, 32);
    GLOAD(q3, dp, 48);  GLOAD(q4, dp, 64);  GLOAD(q5, dp, 80);
    GLOAD(q6, dp, 96);  GLOAD(q7, dp, 112); GLOAD(q8, dp, 128);
    GLOAD(p0, rp, 0);   GLOAD(p1, rp, 16);  GLOAD(p2, rp, 32);
    GLOAD(p3, rp, 48);  GLOAD(p4, rp, 64);  GLOAD(p5, rp, 80);
    GLOAD(p6, rp, 96);  GLOAD(p7, rp, 112); GLOAD(p8, rp, 128);

    // ---- 5. barrier, then per-plane readback + float4 S^T stores ----
    __syncthreads();
    {
        const int w = t >> 6, l = t & 63;
        const f4* lds4 = reinterpret_cast<const f4*>(lds);   // row stride 65 f4
        float* so = Sout + (size_t)b * 36 * HWC + pixbase + 4 * l;
#pragma unroll
        for (int s = 0; s < 9; ++s) {
            const int j = s * 4 + w;                          // plane id
            f4 v = lds4[j * (LROW / 4) + l];
            *reinterpret_cast<f4*>(so + (size_t)j * HWC) = v;
        }
    }

    // ---- 6. wait for D/R only (9 S^T stores are newer; outstanding<=9
    //         with in-order retirement => all D/R loads retired) ----
    asm volatile("s_waitcnt vmcnt(9)" ::: "memory");
    __builtin_amdgcn_sched_barrier(0);   // rule #18

    // ---- unpack to named scalars ----
    float d00=q0.x, d01=q0.y, d02=q0.z, d03=q0.w;
    float d04=q1.x, d05=q1.y, d10=q1.z, d11=q1.w;
    float d12=q2.x, d13=q2.y, d14=q2.z, d15=q2.w;
    float d20=q3.x, d21=q3.y, d22=q3.z, d23=q3.w;
    float d24=q4.x, d25=q4.y, d30=q4.z, d31=q4.w;
    float d32=q5.x, d33=q5.y, d34=q5.z, d35=q5.w;
    float d40=q6.x, d41=q6.y, d42=q6.z, d43=q6.w;
    float d44=q7.x, d45=q7.y, d50=q7.z, d51=q7.w;
    float d52=q8.x, d53=q8.y, d54=q8.z, d55=q8.w;

    float r00=p0.x, r01=p0.y, r02=p0.z, r03=p0.w;
    float r04=p1.x, r05=p1.y, r10=p1.z, r11=p1.w;
    float r12=p2.x, r13=p2.y, r14=p2.z, r15=p2.w;
    float r20=p3.x, r21=p3.y, r22=p3.z, r23=p3.w;
    float r24=p4.x, r25=p4.y, r30=p4.z, r31=p4.w;
    float r32=p5.x, r33=p5.y, r34=p5.z, r35=p5.w;
    float r40=p6.x, r41=p6.y, r42=p6.z, r43=p6.w;
    float r44=p7.x, r45=p7.y, r50=p7.z, r51=p7.w;
    float r52=p8.x, r53=p8.y, r54=p8.z, r55=p8.w;

    // ---- LU of D in place, fully unrolled (Doolittle, no pivot; D ~ 2I) ----
    float rd0 = 1.0f/d00;
    float l10 = d10*rd0;
    d11 -= l10*d01; d12 -= l10*d02; d13 -= l10*d03; d14 -= l10*d04; d15 -= l10*d05;
    float l20 = d20*rd0;
    d21 -= l20*d01; d22 -= l20*d02; d23 -= l20*d03; d24 -= l20*d04; d25 -= l20*d05;
    float l30 = d30*rd0;
    d31 -= l30*d01; d32 -= l30*d02; d33 -= l30*d03; d34 -= l30*d04; d35 -= l30*d05;
    float l40 = d40*rd0;
    d41 -= l40*d01; d42 -= l40*d02; d43 -= l40*d03; d44 -= l40*d04; d45 -= l40*d05;
    float l50 = d50*rd0;
    d51 -= l50*d01; d52 -= l50*d02; d53 -= l50*d03; d54 -= l50*d04; d55 -= l50*d05;

    float rd1 = 1.0f/d11;
    float l21 = d21*rd1;
    d22 -= l21*d12; d23 -= l21*d13; d24 -= l21*d14; d25 -= l21*d15;
    float l31 = d31*rd1;
    d32 -= l31*d12; d33 -= l31*d13; d34 -= l31*d14; d35 -= l31*d15;
    float l41 = d41*rd1;
    d42 -= l41*d12; d43 -= l41*d13; d44 -= l41*d14; d45 -= l41*d15;
    float l51 = d51*rd1;
    d52 -= l51*d12; d53 -= l51*d13; d54 -= l51*d14; d55 -= l51*d15;

    float rd2 = 1.0f/d22;
    float l32 = d32*rd2;
    d33 -= l32*d23; d34 -= l32*d24; d35 -= l32*d25;
    float l42 = d42*rd2;
    d43 -= l42*d23; d44 -= l42*d24; d45 -= l42*d25;
    float l52 = d52*rd2;
    d53 -= l52*d23; d54 -= l52*d24; d55 -= l52*d25;

    float rd3 = 1.0f/d33;
    float l43 = d43*rd3;
    d44 -= l43*d34; d45 -= l43*d35;
    float l53 = d53*rd3;
    d54 -= l53*d34; d55 -= l53*d35;

    float rd4 = 1.0f/d44;
    float l54 = d54*rd4;
    d55 -= l54*d45;
    float rd5 = 1.0f/d55;

    // ---- X = D^{-1} * R[0:3,:]^T ----
    float X0_0,X1_0,X2_0,X3_0,X4_0,X5_0;
    float X0_1,X1_1,X2_1,X3_1,X4_1,X5_1;
    float X0_2,X1_2,X2_2,X3_2,X4_2,X5_2;
    SOLVE6(r00,r01,r02,r03,r04,r05, X0_0,X1_0,X2_0,X3_0,X4_0,X5_0);
    SOLVE6(r10,r11,r12,r13,r14,r15, X0_1,X1_1,X2_1,X3_1,X4_1,X5_1);
    SOLVE6(r20,r21,r22,r23,r24,r25, X0_2,X1_2,X2_2,X3_2,X4_2,X5_2);

    // ---- S1c = R * X : Sxx rows 0..2 (a**), Syx rows 3..5 (b**) ----
    float a00=S1(0,0), a01=S1(0,1), a02=S1(0,2);
    float a10=S1(1,0), a11=S1(1,1), a12=S1(1,2);
    float a20=S1(2,0), a21=S1(2,1), a22=S1(2,2);
    float b00=S1(3,0), b01=S1(3,1), b02=S1(3,2);
    float b10=S1(4,0), b11=S1(4,1), b12=S1(4,2);
    float b20=S1(5,0), b21=S1(5,1), b22=S1(5,2);

    // ---- inv(Sxx) via adjugate ----
    float c00 =  (a11*a22 - a12*a21);
    float c01 = -(a10*a22 - a12*a20);
    float c02 =  (a10*a21 - a11*a20);
    float det = a00*c00 + a01*c01 + a02*c02;
    float rdet = 1.0f / det;
    float i00 = c00*rdet;
    float i01 = -(a01*a22 - a02*a21)*rdet;
    float i02 =  (a01*a12 - a02*a11)*rdet;
    float i10 = c01*rdet;
    float i11 =  (a00*a22 - a02*a20)*rdet;
    float i12 = -(a00*a12 - a02*a10)*rdet;
    float i20 = c02*rdet;
    float i21 = -(a00*a21 - a01*a20)*rdet;
    float i22 =  (a00*a11 - a01*a10)*rdet;

    // ---- Q = Syx * inv(Sxx) ----
    float Q00 = b00*i00 + b01*i10 + b02*i20;
    float Q01 = b00*i01 + b01*i11 + b02*i21;
    float Q02 = b00*i02 + b01*i12 + b02*i22;
    float Q10 = b10*i00 + b11*i10 + b12*i20;
    float Q11 = b10*i01 + b11*i11 + b12*i21;
    float Q12 = b10*i02 + b11*i12 + b12*i22;
    float Q20 = b20*i00 + b21*i10 + b22*i20;
    float Q21 = b20*i01 + b21*i11 + b22*i21;
    float Q22 = b20*i02 + b21*i12 + b22*i22;

    // ---- z = [dx, Q dx] ----
    float z0 = xv0 - mv0, z1v = xv1 - mv1, z2v = xv2 - mv2;
    float z3 = Q00*z0 + Q01*z1v + Q02*z2v;
    float z4 = Q10*z0 + Q11*z1v + Q12*z2v;
    float z5 = Q20*z0 + Q21*z1v + Q22*z2v;

    // ---- w = R z, rows 0..2 negated ----
    float w0 = -(r00*z0 + r01*z1v + r02*z2v + r03*z3 + r04*z4 + r05*z5);
    float w1 = -(r10*z0 + r11*z1v + r12*z2v + r13*z3 + r14*z4 + r15*z5);
    float w2 = -(r20*z0 + r21*z1v + r22*z2v + r23*z3 + r24*z4 + r25*z5);
    float w3 =  (r30*z0 + r31*z1v + r32*z2v + r33*z3 + r34*z4 + r35*z5);
    float w4 =  (r40*z0 + r41*z1v + r42*z2v + r43*z3 + r44*z4 + r45*z5);
    float w5 =  (r50*z0 + r51*z1v + r52*z2v + r53*z3 + r54*z4 + r55*z5);

    // ---- z2 = R^T w + m ----
    float o0 = w0*r00 + w1*r10 + w2*r20 + w3*r30 + w4*r40 + w5*r50 + mv0;
    float o1 = w0*r01 + w1*r11 + w2*r21 + w3*r31 + w4*r41 + w5*r51 + mv1;
    float o2 = w0*r02 + w1*r12 + w2*r22 + w3*r32 + w4*r42 + w5*r52 + mv2;
    float o3 = w0*r03 + w1*r13 + w2*r23 + w3*r33 + w4*r43 + w5*r53 + mv3;
    float o4 = w0*r04 + w1*r14 + w2*r24 + w3*r34 + w4*r44 + w5*r54 + mv4;
    float o5 = w0*r05 + w1*r15 + w2*r25 + w3*r35 + w4*r45 + w5*r55 + mv5;

    // ---- writes (coalesced plane-strided) ----
    xout[xb] = o0; xout[xb + (size_t)HWC] = o1; xout[xb + 2*(size_t)HWC] = o2;
    yout[xb] = o3; yout[xb + (size_t)HWC] = o4; yout[xb + 2*(size_t)HWC] = o5;
    mout[mb]                    = mv0;
    mout[mb + (size_t)HWC]      = mv1;
    mout[mb + 2*(size_t)HWC]    = mv2;
    mout[mb + 3*(size_t)HWC]    = mv3;
    mout[mb + 4*(size_t)HWC]    = mv4;
    mout[mb + 5*(size_t)HWC]    = mv5;
}

extern "C" void kernel_launch(void* const* d_in, const int* in_sizes, int n_in,
                              void* d_out, int out_size, void* d_ws, size_t ws_size,
                              hipStream_t stream) {
    // setup_inputs order: x, y(unused), m, S, R, D
    const float* x  = (const float*)d_in[0];
    const float* m  = (const float*)d_in[2];
    const float* S  = (const float*)d_in[3];
    const float* R  = (const float*)d_in[4];
    const float* D  = (const float*)d_in[5];

    float* out = (float*)d_out;
    const size_t N3 = (size_t)BATCH * 3 * HWC;   // 3,145,728
    const size_t N6 = (size_t)BATCH * 6 * HWC;   // 6,291,456
    float* xout = out;
    float* yout = out + N3;
    float* mout = out + 2 * N3;
    float* Sout = out + 2 * N3 + N6;

    gpenc_fused<<<NPIX / 256, 256, 0, stream>>>(x, m, S, R, D,
                                                xout, yout, mout, Sout);
}